// Round 15
// baseline (4091.450 us; speedup 1.0000x reference)
//
#include <hip/hip_runtime.h>

// Encoder: 3x [conv1d(K=5,pad2)+BN+ReLU] -> biLSTM(H=256) zoneout(0.1).  MFMA convs/gates; VALU recurrence.
// r15 lstm: raw s_barrier (lgkmcnt-only drain; no vmcnt(0) -- stores/loads stay in flight across barriers)
//           + G-loads software-pipelined one step ahead. Weight streaming unchanged from r13.
// ws:    A f16 [32][1000][512] @0 (32,768,000) | G f16 [2][100][32][1024] @32,768,000 (13,107,200)
//        | state @45,875,200 (131,072) | W16 @46,006,272 (1,048,576) | Wg f16 [2][1024][512] @47,054,848 (2,097,152)
//        -> 49,152,000 B
// d_out: Bd (conv1 out) @0 | Wp0 @36,000,000 | Wp1 @36,409,600 | Wp2 @41,652,480 | Xt0 @46,895,360

#define T_LEN 1000
#define NBATCH 32
#define CCH 512
#define HDIM 256
#define GDIM 1024
#define TC 100

typedef _Float16 h16;
typedef _Float16 h16x2 __attribute__((ext_vector_type(2)));
typedef _Float16 f16x8 __attribute__((ext_vector_type(8)));
typedef float    f32x4 __attribute__((ext_vector_type(4)));

__device__ __forceinline__ float fixup(float v, float alt){
    union { float f; unsigned u; } c; c.f = v;
    return ((c.u & 0x7f800000u) == 0x7f800000u) ? alt : v;
}
__device__ __forceinline__ float clamp_s(float v, float lo, float hi){
    return fminf(fmaxf(v, lo), hi);
}
__device__ __forceinline__ float sigm(float x){
    const float xc = clamp_s(x, -30.f, 30.f);
    return 1.0f / (1.0f + __expf(-xc));
}
__device__ __forceinline__ float tanh_safe(float x){
    const float ax = fminf(fabsf(x), 30.0f);
    const float t  = __expf(-2.0f * ax);
    const float r  = (1.0f - t) / (1.0f + t);
    return copysignf(r, x);
}
__device__ __forceinline__ float mac2(unsigned hp, unsigned wp, float acc){
    union Cv { unsigned u; h16 h[2]; };
    Cv a, b; a.u = hp; b.u = wp;
    acc += (float)a.h[0] * (float)b.h[0];
    acc += (float)a.h[1] * (float)b.h[1];
    return acc;
}
__device__ __forceinline__ float dot2(unsigned hp, unsigned wp, float acc){
#if defined(__has_builtin) && __has_builtin(__builtin_amdgcn_fdot2)
    union Cv { unsigned u; h16x2 v; };
    Cv a, b; a.u = hp; b.u = wp;
    return __builtin_amdgcn_fdot2(a.v, b.v, acc, false);
#else
    return mac2(hp, wp, acc);
#endif
}
__device__ __forceinline__ unsigned packh2(float x, float y){
    union Cv { unsigned u; h16 h[2]; };
    Cv c; c.h[0] = (h16)x; c.h[1] = (h16)y;
    return c.u;
}

// Raw workgroup barrier: drains LDS ops only (lgkmcnt), NOT vmcnt -- global loads/stores
// stay in flight across the barrier (hipcc's __syncthreads would emit vmcnt(0) too).
__device__ __forceinline__ void bar_lds_only(){
    __builtin_amdgcn_sched_barrier(0);
    asm volatile("s_waitcnt lgkmcnt(0)" ::: "memory");
    __builtin_amdgcn_sched_barrier(0);
    __builtin_amdgcn_s_barrier();
    __builtin_amdgcn_sched_barrier(0);
}

// ---------------- packs ----------------
// cw f32 [512][cin][5] -> Wp f16 [5][512][cin]
__global__ __launch_bounds__(256)
void pack_convw_kernel(const float* __restrict__ cw, h16* __restrict__ Wp, int cin)
{
    const int n = blockIdx.x*256 + threadIdx.x;
    if (n >= 5*512*cin) return;
    const int k   = n / (512*cin);
    const int rem = n - k*512*cin;
    const int co  = rem / cin;
    const int ci  = rem - co*cin;
    Wp[n] = (h16)cw[((size_t)co*cin + ci)*5 + k];
}

// wih f32 [1024][512] x2 -> Wg f16 [2][1024][512]
__global__ __launch_bounds__(256)
void pack_wih_kernel(const float* __restrict__ wf, const float* __restrict__ wb, h16* __restrict__ Wg)
{
    const int n = blockIdx.x*256 + threadIdx.x;
    const float* src = (n < 1024*512) ? wf : wb;
    Wg[n] = (h16)src[n & (1024*512 - 1)];
}

// whh f32 -> chunk-major stream pack (unchanged from r13).
// Thread t: half=(t>>6)&1, q=t>>7, l=t&63; rows rA=q*128+2l, rB=rA+1; k-pairs P in [64*half, 64*half+64).
// Layout (u32 addr = dir*131072 + chunk*4096 + t*4 + e), chunk 0..31:
//   chunk 0..6   (global stream, rowA tail) : row=rA, P=64*half+4*(9+chunk)+e
//   chunk 7..22  (global stream, rowB)      : row=rB, P=64*half+4*(chunk-7)+e
//   chunk 23..31 (LDS slab,     rowA head)  : row=rA, P=64*half+4*(chunk-23)+e
__global__ __launch_bounds__(256)
void whh_prep_kernel(const float* __restrict__ whh_f, const float* __restrict__ whh_b,
                     unsigned* __restrict__ W16)
{
    const int n = blockIdx.x * 256 + threadIdx.x;   // 262144
    if (n >= 2*128*1024) return;
    const int dir   = n >> 17;
    const int rem   = n & 131071;
    const int chunk = rem >> 12;
    const int idx   = rem & 4095;
    const int t     = idx >> 2;
    const int e     = idx & 3;
    const float* whh = dir ? whh_b : whh_f;
    const int half = (t >> 6) & 1;
    const int q    = t >> 7;
    const int l    = t & 63;
    const int rA   = q*128 + 2*l;
    int row, P;
    if (chunk < 7)       { row = rA;     P = 64*half + 4*(9 + chunk) + e; }
    else if (chunk < 23) { row = rA + 1; P = 64*half + 4*(chunk - 7) + e; }
    else                 { row = rA;     P = 64*half + 4*(chunk - 23) + e; }
    W16[n] = packh2(whh[(size_t)row*HDIM + 2*P], whh[(size_t)row*HDIM + 2*P + 1]);
}

// x f32 [32][80][1000] -> Xt0 f16 [32][1000][80]
__global__ __launch_bounds__(256)
void x0_transpose_kernel(const float* __restrict__ x, h16* __restrict__ Xt0)
{
    const int b = blockIdx.y;
    const int t = blockIdx.x*256 + threadIdx.x;
    if (t >= T_LEN) return;
    h16 v[80];
    #pragma unroll
    for (int c = 0; c < 80; ++c) v[c] = (h16)x[((size_t)b*80 + c)*T_LEN + t];
    #pragma unroll
    for (int g = 0; g < 10; ++g)
        *(f16x8*)(Xt0 + ((size_t)b*T_LEN + t)*80 + g*8) = *(const f16x8*)(v + g*8);
}

// ---------------- conv (implicit GEMM, MFMA 16x16x32 f16) ----------------
__global__ __attribute__((amdgpu_flat_work_group_size(512,512), amdgpu_waves_per_eu(4,4)))
void conv_mfma_kernel(const h16* __restrict__ Xt, const h16* __restrict__ Wp,
                      h16* __restrict__ outp,
                      const float* __restrict__ cb, const float* __restrict__ bg,
                      const float* __restrict__ bb, const float* __restrict__ bm,
                      const float* __restrict__ bv, int cin)
{
    const int t0   = blockIdx.x * 128;
    const int co0  = blockIdx.y * 128;
    const int b    = blockIdx.z;
    const int tid  = threadIdx.x;
    const int lane = tid & 63;
    const int w    = tid >> 6;
    const int wm   = w >> 2;
    const int wn   = w & 3;
    const int lr   = lane & 15;
    const int lg   = lane >> 4;

    __shared__ __align__(16) h16 Xs[132*40];
    __shared__ __align__(16) h16 Ws[5*128*40];

    f32x4 acc[4][2];
    #pragma unroll
    for (int m = 0; m < 4; ++m)
        #pragma unroll
        for (int n = 0; n < 2; ++n)
            #pragma unroll
            for (int r = 0; r < 4; ++r) acc[m][n][r] = 0.f;

    const int ksteps = (cin + 31) >> 5;
    for (int cs = 0; cs < ksteps; ++cs) {
        const int c0 = cs << 5;
        for (int id = tid; id < 132*4; id += 512) {
            const int row = id >> 2, g = id & 3;
            const int t = t0 + row - 2;
            f16x8 v;
            #pragma unroll
            for (int j = 0; j < 8; ++j) v[j] = (h16)0.f;
            if (t >= 0 && t < T_LEN) {
                const int c = c0 + g*8;
                if (c + 8 <= cin) {
                    v = *(const f16x8*)(Xt + ((size_t)b*T_LEN + t)*cin + c);
                } else if (c < cin) {
                    #pragma unroll
                    for (int j = 0; j < 8; ++j) if (c + j < cin) v[j] = Xt[((size_t)b*T_LEN + t)*cin + c + j];
                }
            }
            *(f16x8*)(Xs + row*40 + g*8) = v;
        }
        for (int id = tid; id < 5*128*4; id += 512) {
            const int k  = id >> 9;
            const int co = (id >> 2) & 127;
            const int g  = id & 3;
            const int c  = c0 + g*8;
            f16x8 v;
            #pragma unroll
            for (int j = 0; j < 8; ++j) v[j] = (h16)0.f;
            if (c + 8 <= cin) {
                v = *(const f16x8*)(Wp + ((size_t)k*512 + co0 + co)*cin + c);
            } else if (c < cin) {
                #pragma unroll
                for (int j = 0; j < 8; ++j) if (c + j < cin) v[j] = Wp[((size_t)k*512 + co0 + co)*cin + c + j];
            }
            *(f16x8*)(Ws + (k*128 + co)*40 + g*8) = v;
        }
        __syncthreads();

        #pragma unroll
        for (int k = 0; k < 5; ++k) {
            const f16x8 b0 = *(const f16x8*)(Ws + (k*128 + wn*32 +      lr)*40 + lg*8);
            const f16x8 b1 = *(const f16x8*)(Ws + (k*128 + wn*32 + 16 + lr)*40 + lg*8);
            #pragma unroll
            for (int m = 0; m < 4; ++m) {
                const f16x8 a = *(const f16x8*)(Xs + (wm*64 + m*16 + lr + k)*40 + lg*8);
                acc[m][0] = __builtin_amdgcn_mfma_f32_16x16x32_f16(a, b0, acc[m][0], 0, 0, 0);
                acc[m][1] = __builtin_amdgcn_mfma_f32_16x16x32_f16(a, b1, acc[m][1], 0, 0, 0);
            }
        }
        __syncthreads();
    }

    #pragma unroll
    for (int nf = 0; nf < 2; ++nf) {
        const int co = co0 + wn*32 + nf*16 + lr;
        const float s  = bg[co] * rsqrtf(fmaxf(bv[co] + 1e-5f, 1e-8f));
        const float sh = (cb[co] - bm[co]) * s + bb[co];
        #pragma unroll
        for (int m = 0; m < 4; ++m) {
            #pragma unroll
            for (int r = 0; r < 4; ++r) {
                const int t = t0 + wm*64 + m*16 + lg*4 + r;
                if (t < T_LEN) {
                    const float y = fixup(clamp_s(fmaxf(acc[m][nf][r]*s + sh, 0.f), 0.f, 60000.f), 0.f);
                    outp[((size_t)b*T_LEN + t)*CCH + co] = (h16)y;
                }
            }
        }
    }
}

// ---------------- gates GEMM (MFMA), one time-chunk, both dirs ----------------
__global__ __attribute__((amdgpu_flat_work_group_size(256,256), amdgpu_waves_per_eu(4,4)))
void gates_mfma_kernel(const h16* __restrict__ Xt,
                       const h16* __restrict__ Wg,
                       const float* __restrict__ bih_f, const float* __restrict__ bhh_f,
                       const float* __restrict__ bih_b, const float* __restrict__ bhh_b,
                       h16* __restrict__ G, int t0f, int t0b)
{
    const int tt   = blockIdx.x;
    const int r0   = blockIdx.y * 128;
    const int b    = blockIdx.z & 31;
    const int dir  = blockIdx.z >> 5;
    const int t0c  = dir ? t0b : t0f;
    const int tid  = threadIdx.x;
    const int lane = tid & 63;
    const int w    = tid >> 6;
    const int lr   = lane & 15;
    const int lg   = lane >> 4;
    const float* bi = dir ? bih_b : bih_f;
    const float* bh = dir ? bhh_b : bhh_f;
    const h16* Wd = Wg + (size_t)dir*1024*512;

    __shared__ __align__(16) h16 Xs[64*40];
    __shared__ __align__(16) h16 Ws[128*40];

    f32x4 acc[4][2];
    #pragma unroll
    for (int m = 0; m < 4; ++m)
        #pragma unroll
        for (int n = 0; n < 2; ++n)
            #pragma unroll
            for (int r = 0; r < 4; ++r) acc[m][n][r] = 0.f;

    for (int cs = 0; cs < 16; ++cs) {
        const int c0 = cs << 5;
        for (int id = tid; id < 64*4; id += 256) {
            const int row = id >> 2, g = id & 3;
            int t = t0c + tt*64 + row; if (t >= T_LEN) t = T_LEN - 1;
            *(f16x8*)(Xs + row*40 + g*8) = *(const f16x8*)(Xt + ((size_t)b*T_LEN + t)*CCH + c0 + g*8);
        }
        for (int id = tid; id < 128*4; id += 256) {
            const int row = id >> 2, g = id & 3;
            *(f16x8*)(Ws + row*40 + g*8) = *(const f16x8*)(Wd + (size_t)(r0 + row)*CCH + c0 + g*8);
        }
        __syncthreads();

        const f16x8 b0 = *(const f16x8*)(Ws + (w*32 +      lr)*40 + lg*8);
        const f16x8 b1 = *(const f16x8*)(Ws + (w*32 + 16 + lr)*40 + lg*8);
        #pragma unroll
        for (int m = 0; m < 4; ++m) {
            const f16x8 a = *(const f16x8*)(Xs + (m*16 + lr)*40 + lg*8);
            acc[m][0] = __builtin_amdgcn_mfma_f32_16x16x32_f16(a, b0, acc[m][0], 0, 0, 0);
            acc[m][1] = __builtin_amdgcn_mfma_f32_16x16x32_f16(a, b1, acc[m][1], 0, 0, 0);
        }
        __syncthreads();
    }

    #pragma unroll
    for (int nf = 0; nf < 2; ++nf) {
        const int row = r0 + w*32 + nf*16 + lr;
        const float bias = bi[row] + bh[row];
        #pragma unroll
        for (int m = 0; m < 4; ++m) {
            #pragma unroll
            for (int r = 0; r < 4; ++r) {
                const int tl = tt*64 + m*16 + lg*4 + r;
                if (tl < TC)
                    G[(((size_t)dir*TC + tl)*NBATCH + b)*GDIM + row]
                        = (h16)fixup(clamp_s(acc[m][nf][r] + bias, -60000.f, 60000.f), 0.f);
            }
        }
    }
}

// ---------------- persistent biLSTM recurrence: L2 streaming + raw barriers + G prefetch ----------------
// Thread t: half=(t>>6)&1 (wave parity = k-half), q=t>>7, l=t&63; rows rA=q*128+2l, rB=rA+1.
// r15: barriers drain lgkmcnt only (global loads/stores pipeline across steps); G-loads one step ahead.
__global__ __attribute__((amdgpu_flat_work_group_size(1024, 1024), amdgpu_waves_per_eu(4, 4)))
void lstm_chunk_kernel(const h16* __restrict__ G,
                       const unsigned* __restrict__ W16,
                       float* __restrict__ state,
                       float* __restrict__ out,
                       int t0f, int t0b, int first)
{
    const int tid  = threadIdx.x;
    const int lane = tid & 63;
    const int half = (tid >> 6) & 1;
    const int q    = tid >> 7;
    const int dir  = blockIdx.x >> 5;
    const int b    = blockIdx.x & 31;
    const int t0   = dir ? t0b : t0f;
    float* st = state + ((size_t)(dir*NBATCH + b))*2*HDIM;
    const uint4* Wg4 = (const uint4*)W16 + (size_t)dir*32768;   // 32 chunks x 1024 uint4
    const uint4* Wl4 = Wg4 + 23*1024;                            // LDS-slab source (chunks 23..31)

    __shared__ __align__(16) uint4 lw4[9*1024];        // 144 KB: rowA chunks 0..8
    __shared__ __align__(16) unsigned hs[HDIM/2];      // h as 128 f16-pairs
    __shared__ float pbuf[2*GDIM];                     // [half][row] partials, 8 KB

    #pragma unroll
    for (int s = 0; s < 9; ++s)
        lw4[s*1024 + tid] = Wl4[s*1024 + tid];         // coalesced 16B/thread

    float hst = 0.0f, cst = 0.0f;
    if (tid < HDIM && !first) { hst = st[tid]; cst = st[HDIM + tid]; }
    if (tid < HDIM/2) {
        const float h0 = first ? 0.0f : st[2*tid];
        const float h1 = first ? 0.0f : st[2*tid + 1];
        hs[tid] = packh2(h0, h1);
    }
    __syncthreads();

    float2* pbuf2 = (float2*)pbuf;
    float prev_h = 0.0f;
    int   prev_t = -1;

    // G prefetch pipeline: gn* holds step i's gates, loaded during step i-1 (prologue for i=0)
    float gn0 = 0.f, gn1 = 0.f, gn2 = 0.f, gn3 = 0.f;
    {
        const int sl0 = dir ? (TC - 1) : 0;
        const h16* gp0 = G + (((size_t)dir*TC + sl0)*NBATCH + b)*GDIM;
        if (tid < HDIM) {
            gn0 = (float)gp0[tid];
            gn1 = (float)gp0[HDIM + tid];
            gn2 = (float)gp0[2*HDIM + tid];
            gn3 = (float)gp0[3*HDIM + tid];
        }
    }

    for (int i = 0; i < TC; ++i) {
        const int sl = dir ? (TC - 1 - i) : i;
        const int t  = t0 + sl;

        const unsigned wv = hs[(half << 6) | lane];     // 1 ds_read_b32; lane j holds h-pair 64*half+j

        // prologue prefetch: rowB depth-3, LDS rowA depth-2
        uint4 b0 = Wg4[7*1024 + tid];
        uint4 b1 = Wg4[8*1024 + tid];
        uint4 b2 = Wg4[9*1024 + tid];
        uint4 l0 = lw4[tid];
        uint4 l1 = lw4[1024 + tid];
        uint4 a0{}, a1{}, a2{};

        const float g0 = gn0, g1 = gn1, g2 = gn2, g3 = gn3;   // this step's gates (prefetched)
        if (tid < HDIM && prev_t >= 0)                  // deferred store; no barrier drains it now
            out[((size_t)b*T_LEN + prev_t)*(2*HDIM) + dir*HDIM + tid] = prev_h;

        float aA0 = 0.f, aA1 = 0.f, aB0 = 0.f, aB1 = 0.f;
        #pragma unroll
        for (int c = 0; c < 16; ++c) {
            const uint4 wa = (c < 9) ? l0 : a0;         // rowA source
            const uint4 wb = b0;                        // rowB source
            // rotate + issue next loads (independent of the dots below; scheduler hoists)
            b0 = b1; b1 = b2;
            if (c + 3 < 16) b2 = Wg4[(7 + c + 3)*1024 + tid];
            if (c < 9) { l0 = l1; if (c + 2 < 9) l1 = lw4[(c + 2)*1024 + tid]; }
            else       { a0 = a1; a1 = a2; }
            if (c >= 6 && c < 13) {                     // load rowA-tail chunk (c-6), used at c+3
                const uint4 av = Wg4[(c - 6)*1024 + tid];
                if      (c == 6) a0 = av;
                else if (c == 7) a1 = av;
                else             a2 = av;
            }
            // consume: h pairs j = 4c..4c+3
            const unsigned s0 = (unsigned)__builtin_amdgcn_readlane((int)wv, 4*c + 0);
            const unsigned s1 = (unsigned)__builtin_amdgcn_readlane((int)wv, 4*c + 1);
            const unsigned s2 = (unsigned)__builtin_amdgcn_readlane((int)wv, 4*c + 2);
            const unsigned s3 = (unsigned)__builtin_amdgcn_readlane((int)wv, 4*c + 3);
            aA0 = dot2(s0, wa.x, aA0);  aA1 = dot2(s1, wa.y, aA1);
            aA0 = dot2(s2, wa.z, aA0);  aA1 = dot2(s3, wa.w, aA1);
            aB0 = dot2(s0, wb.x, aB0);  aB1 = dot2(s1, wb.y, aB1);
            aB0 = dot2(s2, wb.z, aB0);  aB1 = dot2(s3, wb.w, aB1);
        }

        // prefetch next step's gates (consumed at elementwise i+1; ~1.5 phases of slack)
        if (i + 1 < TC && tid < HDIM) {
            const int sln = dir ? (TC - 2 - i) : (i + 1);
            const h16* gpn = G + (((size_t)dir*TC + sln)*NBATCH + b)*GDIM;
            gn0 = (float)gpn[tid];
            gn1 = (float)gpn[HDIM + tid];
            gn2 = (float)gpn[2*HDIM + tid];
            gn3 = (float)gpn[3*HDIM + tid];
        }

        // partials for rows rA=q*128+2l (x) and rB=rA+1 (y)
        pbuf2[(half << 9) | (q << 6) | lane] = make_float2(aA0 + aA1, aB0 + aB1);
        bar_lds_only();                                 // pbuf visible; vmem stays in flight

        if (tid < HDIM) {
            const float gi = g0 + pbuf[tid]            + pbuf[GDIM + tid];
            const float gf = g1 + pbuf[HDIM + tid]     + pbuf[GDIM + HDIM + tid];
            const float gg = g2 + pbuf[2*HDIM + tid]   + pbuf[GDIM + 2*HDIM + tid];
            const float go = g3 + pbuf[3*HDIM + tid]   + pbuf[GDIM + 3*HDIM + tid];
            const float c2 = sigm(gf)*cst + sigm(gi)*tanh_safe(gg);
            const float h2 = sigm(go)*tanh_safe(c2);
            hst = 0.1f*hst + 0.9f*h2;                   // zoneout (output is post-zoneout h)
            cst = 0.1f*cst + 0.9f*c2;
            prev_h = fixup(hst, 50.0f);
            prev_t = t;
            const float hn = __shfl_xor(hst, 1);
            if ((tid & 1) == 0) hs[tid >> 1] = packh2(hst, hn);
        }
        bar_lds_only();                                 // hs visible; vmem stays in flight
    }

    if (tid < HDIM) {
        if (prev_t >= 0)
            out[((size_t)b*T_LEN + prev_t)*(2*HDIM) + dir*HDIM + tid] = prev_h;
        st[tid] = hst; st[HDIM + tid] = cst;
    }
}

extern "C" void kernel_launch(void* const* d_in, const int* in_sizes, int n_in,
                              void* d_out, int out_size, void* d_ws, size_t ws_size,
                              hipStream_t stream)
{
    (void)in_sizes; (void)n_in; (void)out_size;
    if (ws_size < 49152000) return;

    const float* x     = (const float*)d_in[0];
    const float* cw0   = (const float*)d_in[1];
    const float* cb0   = (const float*)d_in[2];
    const float* bg0   = (const float*)d_in[3];
    const float* bb0   = (const float*)d_in[4];
    const float* bm0   = (const float*)d_in[5];
    const float* bv0   = (const float*)d_in[6];
    const float* cw1   = (const float*)d_in[7];
    const float* cb1   = (const float*)d_in[8];
    const float* bg1   = (const float*)d_in[9];
    const float* bb1   = (const float*)d_in[10];
    const float* bm1   = (const float*)d_in[11];
    const float* bv1   = (const float*)d_in[12];
    const float* cw2   = (const float*)d_in[13];
    const float* cb2   = (const float*)d_in[14];
    const float* bg2   = (const float*)d_in[15];
    const float* bb2   = (const float*)d_in[16];
    const float* bm2   = (const float*)d_in[17];
    const float* bv2   = (const float*)d_in[18];
    const float* wih_f = (const float*)d_in[19];
    const float* whh_f = (const float*)d_in[20];
    const float* bih_f = (const float*)d_in[21];
    const float* bhh_f = (const float*)d_in[22];
    const float* wih_b = (const float*)d_in[23];
    const float* whh_b = (const float*)d_in[24];
    const float* bih_b = (const float*)d_in[25];
    const float* bhh_b = (const float*)d_in[26];

    char* ws = (char*)d_ws;
    char* od = (char*)d_out;
    h16*      A   = (h16*)(ws);
    h16*      G   = (h16*)(ws + 32768000);
    float*    st  = (float*)(ws + 45875200);
    unsigned* W16 = (unsigned*)(ws + 46006272);
    h16*      Wg  = (h16*)(ws + 47054848);
    h16*      Bd  = (h16*)(od);
    h16*      Wp0 = (h16*)(od + 36000000);
    h16*      Wp1 = (h16*)(od + 36409600);
    h16*      Wp2 = (h16*)(od + 41652480);
    h16*      Xt0 = (h16*)(od + 46895360);
    float*    out = (float*)d_out;

    // packs
    pack_convw_kernel<<<dim3((5*512*80  + 255)/256), 256, 0, stream>>>(cw0, Wp0, 80);
    pack_convw_kernel<<<dim3((5*512*512 + 255)/256), 256, 0, stream>>>(cw1, Wp1, 512);
    pack_convw_kernel<<<dim3((5*512*512 + 255)/256), 256, 0, stream>>>(cw2, Wp2, 512);
    pack_wih_kernel<<<dim3(2*1024*512/256), 256, 0, stream>>>(wih_f, wih_b, Wg);
    whh_prep_kernel<<<dim3(1024), 256, 0, stream>>>(whh_f, whh_b, W16);
    x0_transpose_kernel<<<dim3(4, 32), 256, 0, stream>>>(x, Xt0);

    // convs (implicit-GEMM MFMA)
    const dim3 cgrid(8, 4, 32);
    conv_mfma_kernel<<<cgrid, 512, 0, stream>>>(Xt0, Wp0, A,  cb0, bg0, bb0, bm0, bv0, 80);
    conv_mfma_kernel<<<cgrid, 512, 0, stream>>>(A,   Wp1, Bd, cb1, bg1, bb1, bm1, bv1, 512);
    conv_mfma_kernel<<<cgrid, 512, 0, stream>>>(Bd,  Wp2, A,  cb2, bg2, bb2, bm2, bv2, 512);

    for (int c = 0; c < T_LEN / TC; ++c) {
        const int t0f = c * TC;
        const int t0b = (T_LEN - TC) - c * TC;
        gates_mfma_kernel<<<dim3(2, 8, 64), 256, 0, stream>>>(A, Wg, bih_f, bhh_f, bih_b, bhh_b, G, t0f, t0b);
        lstm_chunk_kernel<<<dim3(64), 1024, 0, stream>>>(G, W16, st, out, t0f, t0b, c == 0);
    }
}

// Round 16
// 3733.829 us; speedup vs baseline: 1.0958x; 1.0958x over previous
//
#include <hip/hip_runtime.h>

// Encoder: 3x [conv1d(K=5,pad2)+BN+ReLU] -> biLSTM(H=256) zoneout(0.1).  MFMA convs/gates; VALU recurrence.
// r16 lstm: ONE barrier/step. Thread-local h-pair (p=64*half+lane) + all-thread redundant elementwise
//   (8 q-replicas) -- no hs LDS, no serial-wave tail, no barrier-2. pbuf double-buffered (WAR-safe).
//   Weight streaming per r13 (8 LDS chunks + 24 L2-streamed, depth-3 rotation). r15's fences/gn reverted.
// ws:    A f16 [32][1000][512] @0 (32,768,000) | G f16 [2][100][32][1024] @32,768,000 (13,107,200)
//        | state @45,875,200 (131,072) | W16 @46,006,272 (1,048,576) | Wg f16 [2][1024][512] @47,054,848 (2,097,152)
//        -> 49,152,000 B
// d_out: Bd (conv1 out) @0 | Wp0 @36,000,000 | Wp1 @36,409,600 | Wp2 @41,652,480 | Xt0 @46,895,360

#define T_LEN 1000
#define NBATCH 32
#define CCH 512
#define HDIM 256
#define GDIM 1024
#define TC 100

typedef _Float16 h16;
typedef _Float16 h16x2 __attribute__((ext_vector_type(2)));
typedef _Float16 f16x8 __attribute__((ext_vector_type(8)));
typedef float    f32x4 __attribute__((ext_vector_type(4)));

__device__ __forceinline__ float fixup(float v, float alt){
    union { float f; unsigned u; } c; c.f = v;
    return ((c.u & 0x7f800000u) == 0x7f800000u) ? alt : v;
}
__device__ __forceinline__ float clamp_s(float v, float lo, float hi){
    return fminf(fmaxf(v, lo), hi);
}
__device__ __forceinline__ float sigm(float x){
    const float xc = clamp_s(x, -30.f, 30.f);
    return 1.0f / (1.0f + __expf(-xc));
}
__device__ __forceinline__ float tanh_safe(float x){
    const float ax = fminf(fabsf(x), 30.0f);
    const float t  = __expf(-2.0f * ax);
    const float r  = (1.0f - t) / (1.0f + t);
    return copysignf(r, x);
}
__device__ __forceinline__ float mac2(unsigned hp, unsigned wp, float acc){
    union Cv { unsigned u; h16 h[2]; };
    Cv a, b; a.u = hp; b.u = wp;
    acc += (float)a.h[0] * (float)b.h[0];
    acc += (float)a.h[1] * (float)b.h[1];
    return acc;
}
__device__ __forceinline__ float dot2(unsigned hp, unsigned wp, float acc){
#if defined(__has_builtin) && __has_builtin(__builtin_amdgcn_fdot2)
    union Cv { unsigned u; h16x2 v; };
    Cv a, b; a.u = hp; b.u = wp;
    return __builtin_amdgcn_fdot2(a.v, b.v, acc, false);
#else
    return mac2(hp, wp, acc);
#endif
}
__device__ __forceinline__ unsigned packh2(float x, float y){
    union Cv { unsigned u; h16 h[2]; };
    Cv c; c.h[0] = (h16)x; c.h[1] = (h16)y;
    return c.u;
}
__device__ __forceinline__ float uplo(unsigned x){
    union Cv { unsigned u; h16 h[2]; } c; c.u = x; return (float)c.h[0];
}
__device__ __forceinline__ float uphi(unsigned x){
    union Cv { unsigned u; h16 h[2]; } c; c.u = x; return (float)c.h[1];
}

// ---------------- packs ----------------
// cw f32 [512][cin][5] -> Wp f16 [5][512][cin]
__global__ __launch_bounds__(256)
void pack_convw_kernel(const float* __restrict__ cw, h16* __restrict__ Wp, int cin)
{
    const int n = blockIdx.x*256 + threadIdx.x;
    if (n >= 5*512*cin) return;
    const int k   = n / (512*cin);
    const int rem = n - k*512*cin;
    const int co  = rem / cin;
    const int ci  = rem - co*cin;
    Wp[n] = (h16)cw[((size_t)co*cin + ci)*5 + k];
}

// wih f32 [1024][512] x2 -> Wg f16 [2][1024][512]
__global__ __launch_bounds__(256)
void pack_wih_kernel(const float* __restrict__ wf, const float* __restrict__ wb, h16* __restrict__ Wg)
{
    const int n = blockIdx.x*256 + threadIdx.x;
    const float* src = (n < 1024*512) ? wf : wb;
    Wg[n] = (h16)src[n & (1024*512 - 1)];
}

// whh f32 -> chunk-major stream pack for r16 lstm (8 LDS chunks + 24 stream chunks).
// Thread t: half=(t>>6)&1, q=t>>7, l=t&63; rows rA=q*128+2l, rB=rA+1; k-pairs P in [64*half, 64*half+64).
// Layout (u32 addr = dir*131072 + chunk*4096 + t*4 + e), chunk 0..31:
//   chunk 0..7   (global stream, rowA tail) : row=rA, P=64*half+4*(8+chunk)+e
//   chunk 8..23  (global stream, rowB)      : row=rB, P=64*half+4*(chunk-8)+e
//   chunk 24..31 (LDS slab,     rowA head)  : row=rA, P=64*half+4*(chunk-24)+e
__global__ __launch_bounds__(256)
void whh_prep_kernel(const float* __restrict__ whh_f, const float* __restrict__ whh_b,
                     unsigned* __restrict__ W16)
{
    const int n = blockIdx.x * 256 + threadIdx.x;   // 262144
    if (n >= 2*128*1024) return;
    const int dir   = n >> 17;
    const int rem   = n & 131071;
    const int chunk = rem >> 12;
    const int idx   = rem & 4095;
    const int t     = idx >> 2;
    const int e     = idx & 3;
    const float* whh = dir ? whh_b : whh_f;
    const int half = (t >> 6) & 1;
    const int q    = t >> 7;
    const int l    = t & 63;
    const int rA   = q*128 + 2*l;
    int row, P;
    if (chunk < 8)       { row = rA;     P = 64*half + 4*(8 + chunk) + e; }
    else if (chunk < 24) { row = rA + 1; P = 64*half + 4*(chunk - 8) + e; }
    else                 { row = rA;     P = 64*half + 4*(chunk - 24) + e; }
    W16[n] = packh2(whh[(size_t)row*HDIM + 2*P], whh[(size_t)row*HDIM + 2*P + 1]);
}

// x f32 [32][80][1000] -> Xt0 f16 [32][1000][80]
__global__ __launch_bounds__(256)
void x0_transpose_kernel(const float* __restrict__ x, h16* __restrict__ Xt0)
{
    const int b = blockIdx.y;
    const int t = blockIdx.x*256 + threadIdx.x;
    if (t >= T_LEN) return;
    h16 v[80];
    #pragma unroll
    for (int c = 0; c < 80; ++c) v[c] = (h16)x[((size_t)b*80 + c)*T_LEN + t];
    #pragma unroll
    for (int g = 0; g < 10; ++g)
        *(f16x8*)(Xt0 + ((size_t)b*T_LEN + t)*80 + g*8) = *(const f16x8*)(v + g*8);
}

// ---------------- conv (implicit GEMM, MFMA 16x16x32 f16) ----------------
__global__ __attribute__((amdgpu_flat_work_group_size(512,512), amdgpu_waves_per_eu(4,4)))
void conv_mfma_kernel(const h16* __restrict__ Xt, const h16* __restrict__ Wp,
                      h16* __restrict__ outp,
                      const float* __restrict__ cb, const float* __restrict__ bg,
                      const float* __restrict__ bb, const float* __restrict__ bm,
                      const float* __restrict__ bv, int cin)
{
    const int t0   = blockIdx.x * 128;
    const int co0  = blockIdx.y * 128;
    const int b    = blockIdx.z;
    const int tid  = threadIdx.x;
    const int lane = tid & 63;
    const int w    = tid >> 6;
    const int wm   = w >> 2;
    const int wn   = w & 3;
    const int lr   = lane & 15;
    const int lg   = lane >> 4;

    __shared__ __align__(16) h16 Xs[132*40];
    __shared__ __align__(16) h16 Ws[5*128*40];

    f32x4 acc[4][2];
    #pragma unroll
    for (int m = 0; m < 4; ++m)
        #pragma unroll
        for (int n = 0; n < 2; ++n)
            #pragma unroll
            for (int r = 0; r < 4; ++r) acc[m][n][r] = 0.f;

    const int ksteps = (cin + 31) >> 5;
    for (int cs = 0; cs < ksteps; ++cs) {
        const int c0 = cs << 5;
        for (int id = tid; id < 132*4; id += 512) {
            const int row = id >> 2, g = id & 3;
            const int t = t0 + row - 2;
            f16x8 v;
            #pragma unroll
            for (int j = 0; j < 8; ++j) v[j] = (h16)0.f;
            if (t >= 0 && t < T_LEN) {
                const int c = c0 + g*8;
                if (c + 8 <= cin) {
                    v = *(const f16x8*)(Xt + ((size_t)b*T_LEN + t)*cin + c);
                } else if (c < cin) {
                    #pragma unroll
                    for (int j = 0; j < 8; ++j) if (c + j < cin) v[j] = Xt[((size_t)b*T_LEN + t)*cin + c + j];
                }
            }
            *(f16x8*)(Xs + row*40 + g*8) = v;
        }
        for (int id = tid; id < 5*128*4; id += 512) {
            const int k  = id >> 9;
            const int co = (id >> 2) & 127;
            const int g  = id & 3;
            const int c  = c0 + g*8;
            f16x8 v;
            #pragma unroll
            for (int j = 0; j < 8; ++j) v[j] = (h16)0.f;
            if (c + 8 <= cin) {
                v = *(const f16x8*)(Wp + ((size_t)k*512 + co0 + co)*cin + c);
            } else if (c < cin) {
                #pragma unroll
                for (int j = 0; j < 8; ++j) if (c + j < cin) v[j] = Wp[((size_t)k*512 + co0 + co)*cin + c + j];
            }
            *(f16x8*)(Ws + (k*128 + co)*40 + g*8) = v;
        }
        __syncthreads();

        #pragma unroll
        for (int k = 0; k < 5; ++k) {
            const f16x8 b0 = *(const f16x8*)(Ws + (k*128 + wn*32 +      lr)*40 + lg*8);
            const f16x8 b1 = *(const f16x8*)(Ws + (k*128 + wn*32 + 16 + lr)*40 + lg*8);
            #pragma unroll
            for (int m = 0; m < 4; ++m) {
                const f16x8 a = *(const f16x8*)(Xs + (wm*64 + m*16 + lr + k)*40 + lg*8);
                acc[m][0] = __builtin_amdgcn_mfma_f32_16x16x32_f16(a, b0, acc[m][0], 0, 0, 0);
                acc[m][1] = __builtin_amdgcn_mfma_f32_16x16x32_f16(a, b1, acc[m][1], 0, 0, 0);
            }
        }
        __syncthreads();
    }

    #pragma unroll
    for (int nf = 0; nf < 2; ++nf) {
        const int co = co0 + wn*32 + nf*16 + lr;
        const float s  = bg[co] * rsqrtf(fmaxf(bv[co] + 1e-5f, 1e-8f));
        const float sh = (cb[co] - bm[co]) * s + bb[co];
        #pragma unroll
        for (int m = 0; m < 4; ++m) {
            #pragma unroll
            for (int r = 0; r < 4; ++r) {
                const int t = t0 + wm*64 + m*16 + lg*4 + r;
                if (t < T_LEN) {
                    const float y = fixup(clamp_s(fmaxf(acc[m][nf][r]*s + sh, 0.f), 0.f, 60000.f), 0.f);
                    outp[((size_t)b*T_LEN + t)*CCH + co] = (h16)y;
                }
            }
        }
    }
}

// ---------------- gates GEMM (MFMA), one time-chunk, both dirs ----------------
__global__ __attribute__((amdgpu_flat_work_group_size(256,256), amdgpu_waves_per_eu(4,4)))
void gates_mfma_kernel(const h16* __restrict__ Xt,
                       const h16* __restrict__ Wg,
                       const float* __restrict__ bih_f, const float* __restrict__ bhh_f,
                       const float* __restrict__ bih_b, const float* __restrict__ bhh_b,
                       h16* __restrict__ G, int t0f, int t0b)
{
    const int tt   = blockIdx.x;
    const int r0   = blockIdx.y * 128;
    const int b    = blockIdx.z & 31;
    const int dir  = blockIdx.z >> 5;
    const int t0c  = dir ? t0b : t0f;
    const int tid  = threadIdx.x;
    const int lane = tid & 63;
    const int w    = tid >> 6;
    const int lr   = lane & 15;
    const int lg   = lane >> 4;
    const float* bi = dir ? bih_b : bih_f;
    const float* bh = dir ? bhh_b : bhh_f;
    const h16* Wd = Wg + (size_t)dir*1024*512;

    __shared__ __align__(16) h16 Xs[64*40];
    __shared__ __align__(16) h16 Ws[128*40];

    f32x4 acc[4][2];
    #pragma unroll
    for (int m = 0; m < 4; ++m)
        #pragma unroll
        for (int n = 0; n < 2; ++n)
            #pragma unroll
            for (int r = 0; r < 4; ++r) acc[m][n][r] = 0.f;

    for (int cs = 0; cs < 16; ++cs) {
        const int c0 = cs << 5;
        for (int id = tid; id < 64*4; id += 256) {
            const int row = id >> 2, g = id & 3;
            int t = t0c + tt*64 + row; if (t >= T_LEN) t = T_LEN - 1;
            *(f16x8*)(Xs + row*40 + g*8) = *(const f16x8*)(Xt + ((size_t)b*T_LEN + t)*CCH + c0 + g*8);
        }
        for (int id = tid; id < 128*4; id += 256) {
            const int row = id >> 2, g = id & 3;
            *(f16x8*)(Ws + row*40 + g*8) = *(const f16x8*)(Wd + (size_t)(r0 + row)*CCH + c0 + g*8);
        }
        __syncthreads();

        const f16x8 b0 = *(const f16x8*)(Ws + (w*32 +      lr)*40 + lg*8);
        const f16x8 b1 = *(const f16x8*)(Ws + (w*32 + 16 + lr)*40 + lg*8);
        #pragma unroll
        for (int m = 0; m < 4; ++m) {
            const f16x8 a = *(const f16x8*)(Xs + (m*16 + lr)*40 + lg*8);
            acc[m][0] = __builtin_amdgcn_mfma_f32_16x16x32_f16(a, b0, acc[m][0], 0, 0, 0);
            acc[m][1] = __builtin_amdgcn_mfma_f32_16x16x32_f16(a, b1, acc[m][1], 0, 0, 0);
        }
        __syncthreads();
    }

    #pragma unroll
    for (int nf = 0; nf < 2; ++nf) {
        const int row = r0 + w*32 + nf*16 + lr;
        const float bias = bi[row] + bh[row];
        #pragma unroll
        for (int m = 0; m < 4; ++m) {
            #pragma unroll
            for (int r = 0; r < 4; ++r) {
                const int tl = tt*64 + m*16 + lg*4 + r;
                if (tl < TC)
                    G[(((size_t)dir*TC + tl)*NBATCH + b)*GDIM + row]
                        = (h16)fixup(clamp_s(acc[m][nf][r] + bias, -60000.f, 60000.f), 0.f);
            }
        }
    }
}

// ---------------- persistent biLSTM recurrence: 1 barrier/step, thread-local h, redundant elementwise ----
// Thread t: half=(t>>6)&1 (wave parity = k-half), q=t>>7, l=t&63; dot rows rA=q*128+2l, rB=rA+1.
// Thread's own h-pair p=64*half+l (units 2p,2p+1) -- exactly what its readlane wave-slot must hold.
// Elementwise for (2p,2p+1) computed redundantly by the 8 q-replicas (identical inputs -> identical fp).
__global__ __attribute__((amdgpu_flat_work_group_size(1024, 1024), amdgpu_waves_per_eu(4, 4)))
void lstm_chunk_kernel(const h16* __restrict__ G,
                       const unsigned* __restrict__ W16,
                       float* __restrict__ state,
                       float* __restrict__ out,
                       int t0f, int t0b, int first)
{
    const int tid  = threadIdx.x;
    const int lane = tid & 63;
    const int half = (tid >> 6) & 1;
    const int q    = tid >> 7;
    const int dir  = blockIdx.x >> 5;
    const int b    = blockIdx.x & 31;
    const int t0   = dir ? t0b : t0f;
    float* st = state + ((size_t)(dir*NBATCH + b))*2*HDIM;
    const uint4* Wg4 = (const uint4*)W16 + (size_t)dir*32768;   // 32 chunks x 1024 uint4
    const uint4* Wl4 = Wg4 + 24*1024;                            // LDS-slab source (chunks 24..31)

    __shared__ __align__(16) uint4 lw4[8*1024];        // 128 KB: rowA chunks 0..7 (pairs 0..31)
    __shared__ __align__(16) float pb[2][2*GDIM];      // 16 KB: double-buffered [half][row] partials

    #pragma unroll
    for (int s = 0; s < 8; ++s)
        lw4[s*1024 + tid] = Wl4[s*1024 + tid];         // coalesced 16B/thread

    const int p  = (half << 6) | lane;                 // this thread's h-pair 0..127
    const int u0 = 2*p;

    float h0f = 0.f, h1f = 0.f, c0s = 0.f, c1s = 0.f;
    if (!first) {
        h0f = st[u0];        h1f = st[u0 + 1];
        c0s = st[HDIM + u0]; c1s = st[HDIM + u0 + 1];
    }
    unsigned wv = packh2(h0f, h1f);
    __syncthreads();

    for (int i = 0; i < TC; ++i) {
        const int sl = dir ? (TC - 1 - i) : i;
        const int t  = t0 + sl;
        const unsigned* gp32 = (const unsigned*)(G + (((size_t)dir*TC + sl)*NBATCH + b)*GDIM);

        // G for this step's elementwise (consumed post-barrier -> latency hides under dots)
        const unsigned gu0 = gp32[0*128 + p];
        const unsigned gu1 = gp32[1*128 + p];
        const unsigned gu2 = gp32[2*128 + p];
        const unsigned gu3 = gp32[3*128 + p];

        // stream prologue: rowB depth-3, LDS rowA depth-2
        uint4 b0 = Wg4[8*1024 + tid];
        uint4 b1 = Wg4[9*1024 + tid];
        uint4 b2 = Wg4[10*1024 + tid];
        uint4 l0 = lw4[tid];
        uint4 l1 = lw4[1024 + tid];
        uint4 a0{}, a1{}, a2{};

        float aA0 = 0.f, aA1 = 0.f, aB0 = 0.f, aB1 = 0.f;
        #pragma unroll
        for (int c = 0; c < 16; ++c) {
            const uint4 wa = (c < 8) ? l0 : a0;         // rowA source
            const uint4 wb = b0;                        // rowB source
            b0 = b1; b1 = b2;
            if (c + 3 < 16) b2 = Wg4[(8 + c + 3)*1024 + tid];
            if (c < 8) { l0 = l1; if (c + 2 < 8) l1 = lw4[(c + 2)*1024 + tid]; }
            else       { a0 = a1; a1 = a2; }
            if (c >= 5 && c < 13) {                     // rowA-tail chunk (c-5), consumed at c+3
                const uint4 av = Wg4[(c - 5)*1024 + tid];
                if      (c == 5) a0 = av;
                else if (c == 6) a1 = av;
                else             a2 = av;
            }
            const unsigned s0 = (unsigned)__builtin_amdgcn_readlane((int)wv, 4*c + 0);
            const unsigned s1 = (unsigned)__builtin_amdgcn_readlane((int)wv, 4*c + 1);
            const unsigned s2 = (unsigned)__builtin_amdgcn_readlane((int)wv, 4*c + 2);
            const unsigned s3 = (unsigned)__builtin_amdgcn_readlane((int)wv, 4*c + 3);
            aA0 = dot2(s0, wa.x, aA0);  aA1 = dot2(s1, wa.y, aA1);
            aA0 = dot2(s2, wa.z, aA0);  aA1 = dot2(s3, wa.w, aA1);
            aB0 = dot2(s0, wb.x, aB0);  aB1 = dot2(s1, wb.y, aB1);
            aB0 = dot2(s2, wb.z, aB0);  aB1 = dot2(s3, wb.w, aB1);
        }
        // partials for rows rA=q*128+2l (x) and rB=rA+1 (y), buffer i&1
        ((float2*)pb[i & 1])[(half << 9) | (q << 6) | lane] = make_float2(aA0 + aA1, aB0 + aB1);
        __syncthreads();                                // the ONLY barrier per step

        // all-thread redundant elementwise for units u0, u0+1
        const float2* pbr2 = (const float2*)pb[i & 1];
        const float2 vi0 = pbr2[0*512 + 0*128 + p], vi1 = pbr2[1*512 + 0*128 + p];
        const float2 vf0 = pbr2[0*512 + 1*128 + p], vf1 = pbr2[1*512 + 1*128 + p];
        const float2 vg0 = pbr2[0*512 + 2*128 + p], vg1 = pbr2[1*512 + 2*128 + p];
        const float2 vo0 = pbr2[0*512 + 3*128 + p], vo1 = pbr2[1*512 + 3*128 + p];

        const float gi0 = uplo(gu0) + vi0.x + vi1.x, gi1 = uphi(gu0) + vi0.y + vi1.y;
        const float gf0 = uplo(gu1) + vf0.x + vf1.x, gf1 = uphi(gu1) + vf0.y + vf1.y;
        const float gg0 = uplo(gu2) + vg0.x + vg1.x, gg1 = uphi(gu2) + vg0.y + vg1.y;
        const float go0 = uplo(gu3) + vo0.x + vo1.x, go1 = uphi(gu3) + vo0.y + vo1.y;

        const float c20 = sigm(gf0)*c0s + sigm(gi0)*tanh_safe(gg0);
        const float c21 = sigm(gf1)*c1s + sigm(gi1)*tanh_safe(gg1);
        const float h20 = sigm(go0)*tanh_safe(c20);
        const float h21 = sigm(go1)*tanh_safe(c21);
        h0f = 0.1f*h0f + 0.9f*h20;  c0s = 0.1f*c0s + 0.9f*c20;   // zoneout
        h1f = 0.1f*h1f + 0.9f*h21;  c1s = 0.1f*c1s + 0.9f*c21;
        const float o0 = fixup(h0f, 50.0f), o1 = fixup(h1f, 50.0f);
        wv = packh2(h0f, h1f);                          // next step's readlane source (local!)
        if (q == 0)
            *(float2*)(out + ((size_t)b*T_LEN + t)*(2*HDIM) + dir*HDIM + u0) = make_float2(o0, o1);
        // no second barrier: next step writes pb[(i+1)&1]; readers of pb[i&1] are pre-barrier(i+1)
    }

    if (q == 0) {
        st[u0] = h0f;        st[u0 + 1] = h1f;
        st[HDIM + u0] = c0s; st[HDIM + u0 + 1] = c1s;
    }
}

extern "C" void kernel_launch(void* const* d_in, const int* in_sizes, int n_in,
                              void* d_out, int out_size, void* d_ws, size_t ws_size,
                              hipStream_t stream)
{
    (void)in_sizes; (void)n_in; (void)out_size;
    if (ws_size < 49152000) return;

    const float* x     = (const float*)d_in[0];
    const float* cw0   = (const float*)d_in[1];
    const float* cb0   = (const float*)d_in[2];
    const float* bg0   = (const float*)d_in[3];
    const float* bb0   = (const float*)d_in[4];
    const float* bm0   = (const float*)d_in[5];
    const float* bv0   = (const float*)d_in[6];
    const float* cw1   = (const float*)d_in[7];
    const float* cb1   = (const float*)d_in[8];
    const float* bg1   = (const float*)d_in[9];
    const float* bb1   = (const float*)d_in[10];
    const float* bm1   = (const float*)d_in[11];
    const float* bv1   = (const float*)d_in[12];
    const float* cw2   = (const float*)d_in[13];
    const float* cb2   = (const float*)d_in[14];
    const float* bg2   = (const float*)d_in[15];
    const float* bb2   = (const float*)d_in[16];
    const float* bm2   = (const float*)d_in[17];
    const float* bv2   = (const float*)d_in[18];
    const float* wih_f = (const float*)d_in[19];
    const float* whh_f = (const float*)d_in[20];
    const float* bih_f = (const float*)d_in[21];
    const float* bhh_f = (const float*)d_in[22];
    const float* wih_b = (const float*)d_in[23];
    const float* whh_b = (const float*)d_in[24];
    const float* bih_b = (const float*)d_in[25];
    const float* bhh_b = (const float*)d_in[26];

    char* ws = (char*)d_ws;
    char* od = (char*)d_out;
    h16*      A   = (h16*)(ws);
    h16*      G   = (h16*)(ws + 32768000);
    float*    st  = (float*)(ws + 45875200);
    unsigned* W16 = (unsigned*)(ws + 46006272);
    h16*      Wg  = (h16*)(ws + 47054848);
    h16*      Bd  = (h16*)(od);
    h16*      Wp0 = (h16*)(od + 36000000);
    h16*      Wp1 = (h16*)(od + 36409600);
    h16*      Wp2 = (h16*)(od + 41652480);
    h16*      Xt0 = (h16*)(od + 46895360);
    float*    out = (float*)d_out;

    // packs
    pack_convw_kernel<<<dim3((5*512*80  + 255)/256), 256, 0, stream>>>(cw0, Wp0, 80);
    pack_convw_kernel<<<dim3((5*512*512 + 255)/256), 256, 0, stream>>>(cw1, Wp1, 512);
    pack_convw_kernel<<<dim3((5*512*512 + 255)/256), 256, 0, stream>>>(cw2, Wp2, 512);
    pack_wih_kernel<<<dim3(2*1024*512/256), 256, 0, stream>>>(wih_f, wih_b, Wg);
    whh_prep_kernel<<<dim3(1024), 256, 0, stream>>>(whh_f, whh_b, W16);
    x0_transpose_kernel<<<dim3(4, 32), 256, 0, stream>>>(x, Xt0);

    // convs (implicit-GEMM MFMA)
    const dim3 cgrid(8, 4, 32);
    conv_mfma_kernel<<<cgrid, 512, 0, stream>>>(Xt0, Wp0, A,  cb0, bg0, bb0, bm0, bv0, 80);
    conv_mfma_kernel<<<cgrid, 512, 0, stream>>>(A,   Wp1, Bd, cb1, bg1, bb1, bm1, bv1, 512);
    conv_mfma_kernel<<<cgrid, 512, 0, stream>>>(Bd,  Wp2, A,  cb2, bg2, bb2, bm2, bv2, 512);

    for (int c = 0; c < T_LEN / TC; ++c) {
        const int t0f = c * TC;
        const int t0b = (T_LEN - TC) - c * TC;
        gates_mfma_kernel<<<dim3(2, 8, 64), 256, 0, stream>>>(A, Wg, bih_f, bhh_f, bih_b, bhh_b, G, t0f, t0b);
        lstm_chunk_kernel<<<dim3(64), 1024, 0, stream>>>(G, W16, st, out, t0f, t0b, c == 0);
    }
}

// Round 17
// 3279.189 us; speedup vs baseline: 1.2477x; 1.1386x over previous
//
#include <hip/hip_runtime.h>

// Encoder: 3x [conv1d(K=5,pad2)+BN+ReLU] -> biLSTM(H=256) zoneout(0.1).  MFMA convs/gates; VALU recurrence.
// r17: production = r13/r14 verbatim (best known: 2.56ms, lstm 210us). lstm templated on VARIANT:
//   V0 production (bit-identical r13) | V1 no-L2-stream | V2 no-dots (loads kept) | V3 cheap-elem | V4 skeleton.
//   4 probe dispatches appended, writing only to dead ws scratch -- per-dispatch rocprof isolates the
//   ~5000 cyc/step budget empirically (stream-BW vs VALU vs skeleton).
// ws:    A f16 [32][1000][512] @0 (32,768,000) | G f16 [2][100][32][1024] @32,768,000 (13,107,200)
//        | state @45,875,200 (131,072) | W16 @46,006,272 (1,048,576) | Wg f16 [2][1024][512] @47,054,848 (2,097,152)
//        -> 49,152,000 B.  Probe scratch: pout @ws+0 (6.6MB), pst @ws+20,000,000 (131KB) -- A is dead there.
// d_out: Bd (conv1 out) @0 | Wp0 @36,000,000 | Wp1 @36,409,600 | Wp2 @41,652,480 | Xt0 @46,895,360

#define T_LEN 1000
#define NBATCH 32
#define CCH 512
#define HDIM 256
#define GDIM 1024
#define TC 100

typedef _Float16 h16;
typedef _Float16 h16x2 __attribute__((ext_vector_type(2)));
typedef _Float16 f16x8 __attribute__((ext_vector_type(8)));
typedef float    f32x4 __attribute__((ext_vector_type(4)));

__device__ __forceinline__ float fixup(float v, float alt){
    union { float f; unsigned u; } c; c.f = v;
    return ((c.u & 0x7f800000u) == 0x7f800000u) ? alt : v;
}
__device__ __forceinline__ float clamp_s(float v, float lo, float hi){
    return fminf(fmaxf(v, lo), hi);
}
__device__ __forceinline__ float sigm(float x){
    const float xc = clamp_s(x, -30.f, 30.f);
    return 1.0f / (1.0f + __expf(-xc));
}
__device__ __forceinline__ float tanh_safe(float x){
    const float ax = fminf(fabsf(x), 30.0f);
    const float t  = __expf(-2.0f * ax);
    const float r  = (1.0f - t) / (1.0f + t);
    return copysignf(r, x);
}
__device__ __forceinline__ float mac2(unsigned hp, unsigned wp, float acc){
    union Cv { unsigned u; h16 h[2]; };
    Cv a, b; a.u = hp; b.u = wp;
    acc += (float)a.h[0] * (float)b.h[0];
    acc += (float)a.h[1] * (float)b.h[1];
    return acc;
}
__device__ __forceinline__ float dot2(unsigned hp, unsigned wp, float acc){
#if defined(__has_builtin) && __has_builtin(__builtin_amdgcn_fdot2)
    union Cv { unsigned u; h16x2 v; };
    Cv a, b; a.u = hp; b.u = wp;
    return __builtin_amdgcn_fdot2(a.v, b.v, acc, false);
#else
    return mac2(hp, wp, acc);
#endif
}
__device__ __forceinline__ unsigned packh2(float x, float y){
    union Cv { unsigned u; h16 h[2]; };
    Cv c; c.h[0] = (h16)x; c.h[1] = (h16)y;
    return c.u;
}

// ---------------- packs ----------------
__global__ __launch_bounds__(256)
void pack_convw_kernel(const float* __restrict__ cw, h16* __restrict__ Wp, int cin)
{
    const int n = blockIdx.x*256 + threadIdx.x;
    if (n >= 5*512*cin) return;
    const int k   = n / (512*cin);
    const int rem = n - k*512*cin;
    const int co  = rem / cin;
    const int ci  = rem - co*cin;
    Wp[n] = (h16)cw[((size_t)co*cin + ci)*5 + k];
}

__global__ __launch_bounds__(256)
void pack_wih_kernel(const float* __restrict__ wf, const float* __restrict__ wb, h16* __restrict__ Wg)
{
    const int n = blockIdx.x*256 + threadIdx.x;
    const float* src = (n < 1024*512) ? wf : wb;
    Wg[n] = (h16)src[n & (1024*512 - 1)];
}

// whh f32 -> chunk-major stream pack (r13 layout).
__global__ __launch_bounds__(256)
void whh_prep_kernel(const float* __restrict__ whh_f, const float* __restrict__ whh_b,
                     unsigned* __restrict__ W16)
{
    const int n = blockIdx.x * 256 + threadIdx.x;   // 262144
    if (n >= 2*128*1024) return;
    const int dir   = n >> 17;
    const int rem   = n & 131071;
    const int chunk = rem >> 12;
    const int idx   = rem & 4095;
    const int t     = idx >> 2;
    const int e     = idx & 3;
    const float* whh = dir ? whh_b : whh_f;
    const int half = (t >> 6) & 1;
    const int q    = t >> 7;
    const int l    = t & 63;
    const int rA   = q*128 + 2*l;
    int row, P;
    if (chunk < 7)       { row = rA;     P = 64*half + 4*(9 + chunk) + e; }
    else if (chunk < 23) { row = rA + 1; P = 64*half + 4*(chunk - 7) + e; }
    else                 { row = rA;     P = 64*half + 4*(chunk - 23) + e; }
    W16[n] = packh2(whh[(size_t)row*HDIM + 2*P], whh[(size_t)row*HDIM + 2*P + 1]);
}

__global__ __launch_bounds__(256)
void x0_transpose_kernel(const float* __restrict__ x, h16* __restrict__ Xt0)
{
    const int b = blockIdx.y;
    const int t = blockIdx.x*256 + threadIdx.x;
    if (t >= T_LEN) return;
    h16 v[80];
    #pragma unroll
    for (int c = 0; c < 80; ++c) v[c] = (h16)x[((size_t)b*80 + c)*T_LEN + t];
    #pragma unroll
    for (int g = 0; g < 10; ++g)
        *(f16x8*)(Xt0 + ((size_t)b*T_LEN + t)*80 + g*8) = *(const f16x8*)(v + g*8);
}

// ---------------- conv (implicit GEMM, MFMA 16x16x32 f16) ----------------
__global__ __attribute__((amdgpu_flat_work_group_size(512,512), amdgpu_waves_per_eu(4,4)))
void conv_mfma_kernel(const h16* __restrict__ Xt, const h16* __restrict__ Wp,
                      h16* __restrict__ outp,
                      const float* __restrict__ cb, const float* __restrict__ bg,
                      const float* __restrict__ bb, const float* __restrict__ bm,
                      const float* __restrict__ bv, int cin)
{
    const int t0   = blockIdx.x * 128;
    const int co0  = blockIdx.y * 128;
    const int b    = blockIdx.z;
    const int tid  = threadIdx.x;
    const int lane = tid & 63;
    const int w    = tid >> 6;
    const int wm   = w >> 2;
    const int wn   = w & 3;
    const int lr   = lane & 15;
    const int lg   = lane >> 4;

    __shared__ __align__(16) h16 Xs[132*40];
    __shared__ __align__(16) h16 Ws[5*128*40];

    f32x4 acc[4][2];
    #pragma unroll
    for (int m = 0; m < 4; ++m)
        #pragma unroll
        for (int n = 0; n < 2; ++n)
            #pragma unroll
            for (int r = 0; r < 4; ++r) acc[m][n][r] = 0.f;

    const int ksteps = (cin + 31) >> 5;
    for (int cs = 0; cs < ksteps; ++cs) {
        const int c0 = cs << 5;
        for (int id = tid; id < 132*4; id += 512) {
            const int row = id >> 2, g = id & 3;
            const int t = t0 + row - 2;
            f16x8 v;
            #pragma unroll
            for (int j = 0; j < 8; ++j) v[j] = (h16)0.f;
            if (t >= 0 && t < T_LEN) {
                const int c = c0 + g*8;
                if (c + 8 <= cin) {
                    v = *(const f16x8*)(Xt + ((size_t)b*T_LEN + t)*cin + c);
                } else if (c < cin) {
                    #pragma unroll
                    for (int j = 0; j < 8; ++j) if (c + j < cin) v[j] = Xt[((size_t)b*T_LEN + t)*cin + c + j];
                }
            }
            *(f16x8*)(Xs + row*40 + g*8) = v;
        }
        for (int id = tid; id < 5*128*4; id += 512) {
            const int k  = id >> 9;
            const int co = (id >> 2) & 127;
            const int g  = id & 3;
            const int c  = c0 + g*8;
            f16x8 v;
            #pragma unroll
            for (int j = 0; j < 8; ++j) v[j] = (h16)0.f;
            if (c + 8 <= cin) {
                v = *(const f16x8*)(Wp + ((size_t)k*512 + co0 + co)*cin + c);
            } else if (c < cin) {
                #pragma unroll
                for (int j = 0; j < 8; ++j) if (c + j < cin) v[j] = Wp[((size_t)k*512 + co0 + co)*cin + c + j];
            }
            *(f16x8*)(Ws + (k*128 + co)*40 + g*8) = v;
        }
        __syncthreads();

        #pragma unroll
        for (int k = 0; k < 5; ++k) {
            const f16x8 b0 = *(const f16x8*)(Ws + (k*128 + wn*32 +      lr)*40 + lg*8);
            const f16x8 b1 = *(const f16x8*)(Ws + (k*128 + wn*32 + 16 + lr)*40 + lg*8);
            #pragma unroll
            for (int m = 0; m < 4; ++m) {
                const f16x8 a = *(const f16x8*)(Xs + (wm*64 + m*16 + lr + k)*40 + lg*8);
                acc[m][0] = __builtin_amdgcn_mfma_f32_16x16x32_f16(a, b0, acc[m][0], 0, 0, 0);
                acc[m][1] = __builtin_amdgcn_mfma_f32_16x16x32_f16(a, b1, acc[m][1], 0, 0, 0);
            }
        }
        __syncthreads();
    }

    #pragma unroll
    for (int nf = 0; nf < 2; ++nf) {
        const int co = co0 + wn*32 + nf*16 + lr;
        const float s  = bg[co] * rsqrtf(fmaxf(bv[co] + 1e-5f, 1e-8f));
        const float sh = (cb[co] - bm[co]) * s + bb[co];
        #pragma unroll
        for (int m = 0; m < 4; ++m) {
            #pragma unroll
            for (int r = 0; r < 4; ++r) {
                const int t = t0 + wm*64 + m*16 + lg*4 + r;
                if (t < T_LEN) {
                    const float y = fixup(clamp_s(fmaxf(acc[m][nf][r]*s + sh, 0.f), 0.f, 60000.f), 0.f);
                    outp[((size_t)b*T_LEN + t)*CCH + co] = (h16)y;
                }
            }
        }
    }
}

// ---------------- gates GEMM (MFMA), one time-chunk, both dirs ----------------
__global__ __attribute__((amdgpu_flat_work_group_size(256,256), amdgpu_waves_per_eu(4,4)))
void gates_mfma_kernel(const h16* __restrict__ Xt,
                       const h16* __restrict__ Wg,
                       const float* __restrict__ bih_f, const float* __restrict__ bhh_f,
                       const float* __restrict__ bih_b, const float* __restrict__ bhh_b,
                       h16* __restrict__ G, int t0f, int t0b)
{
    const int tt   = blockIdx.x;
    const int r0   = blockIdx.y * 128;
    const int b    = blockIdx.z & 31;
    const int dir  = blockIdx.z >> 5;
    const int t0c  = dir ? t0b : t0f;
    const int tid  = threadIdx.x;
    const int lane = tid & 63;
    const int w    = tid >> 6;
    const int lr   = lane & 15;
    const int lg   = lane >> 4;
    const float* bi = dir ? bih_b : bih_f;
    const float* bh = dir ? bhh_b : bhh_f;
    const h16* Wd = Wg + (size_t)dir*1024*512;

    __shared__ __align__(16) h16 Xs[64*40];
    __shared__ __align__(16) h16 Ws[128*40];

    f32x4 acc[4][2];
    #pragma unroll
    for (int m = 0; m < 4; ++m)
        #pragma unroll
        for (int n = 0; n < 2; ++n)
            #pragma unroll
            for (int r = 0; r < 4; ++r) acc[m][n][r] = 0.f;

    for (int cs = 0; cs < 16; ++cs) {
        const int c0 = cs << 5;
        for (int id = tid; id < 64*4; id += 256) {
            const int row = id >> 2, g = id & 3;
            int t = t0c + tt*64 + row; if (t >= T_LEN) t = T_LEN - 1;
            *(f16x8*)(Xs + row*40 + g*8) = *(const f16x8*)(Xt + ((size_t)b*T_LEN + t)*CCH + c0 + g*8);
        }
        for (int id = tid; id < 128*4; id += 256) {
            const int row = id >> 2, g = id & 3;
            *(f16x8*)(Ws + row*40 + g*8) = *(const f16x8*)(Wd + (size_t)(r0 + row)*CCH + c0 + g*8);
        }
        __syncthreads();

        const f16x8 b0 = *(const f16x8*)(Ws + (w*32 +      lr)*40 + lg*8);
        const f16x8 b1 = *(const f16x8*)(Ws + (w*32 + 16 + lr)*40 + lg*8);
        #pragma unroll
        for (int m = 0; m < 4; ++m) {
            const f16x8 a = *(const f16x8*)(Xs + (m*16 + lr)*40 + lg*8);
            acc[m][0] = __builtin_amdgcn_mfma_f32_16x16x32_f16(a, b0, acc[m][0], 0, 0, 0);
            acc[m][1] = __builtin_amdgcn_mfma_f32_16x16x32_f16(a, b1, acc[m][1], 0, 0, 0);
        }
        __syncthreads();
    }

    #pragma unroll
    for (int nf = 0; nf < 2; ++nf) {
        const int row = r0 + w*32 + nf*16 + lr;
        const float bias = bi[row] + bh[row];
        #pragma unroll
        for (int m = 0; m < 4; ++m) {
            #pragma unroll
            for (int r = 0; r < 4; ++r) {
                const int tl = tt*64 + m*16 + lg*4 + r;
                if (tl < TC)
                    G[(((size_t)dir*TC + tl)*NBATCH + b)*GDIM + row]
                        = (h16)fixup(clamp_s(acc[m][nf][r] + bias, -60000.f, 60000.f), 0.f);
            }
        }
    }
}

// ---------------- persistent biLSTM recurrence (r13 structure), templated for ablation ----------------
// V=0 production (bit-identical r13). Probes: V1 no-L2-stream | V2 no-dots (loads kept live) |
// V3 cheap-elementwise | V4 skeleton. Probes write only scratch (pout/pst), TC-local out indexing.
template<int V>
__global__ __attribute__((amdgpu_flat_work_group_size(1024, 1024), amdgpu_waves_per_eu(4, 4)))
void lstm_chunk_kernel(const h16* __restrict__ G,
                       const unsigned* __restrict__ W16,
                       float* __restrict__ state,
                       float* __restrict__ out,
                       int t0f, int t0b, int first)
{
    constexpr bool STREAM = (V == 0 || V == 2 || V == 3);
    constexpr bool DOTS   = (V == 0 || V == 1 || V == 3);
    constexpr bool ELEM   = (V == 0 || V == 1 || V == 2);

    const int tid  = threadIdx.x;
    const int lane = tid & 63;
    const int half = (tid >> 6) & 1;
    const int q    = tid >> 7;
    const int dir  = blockIdx.x >> 5;
    const int b    = blockIdx.x & 31;
    const int t0   = dir ? t0b : t0f;
    float* st = state + ((size_t)(dir*NBATCH + b))*2*HDIM;
    const uint4* Wg4 = (const uint4*)W16 + (size_t)dir*32768;
    const uint4* Wl4 = Wg4 + 23*1024;

    __shared__ __align__(16) uint4 lw4[9*1024];        // 144 KB: rowA chunks 0..8
    __shared__ __align__(16) unsigned hs[HDIM/2];
    __shared__ float pbuf[2*GDIM];

    #pragma unroll
    for (int s = 0; s < 9; ++s)
        lw4[s*1024 + tid] = Wl4[s*1024 + tid];

    float hst = 0.0f, cst = 0.0f;
    if (tid < HDIM && !first) { hst = st[tid]; cst = st[HDIM + tid]; }
    if (tid < HDIM/2) {
        const float h0 = first ? 0.0f : st[2*tid];
        const float h1 = first ? 0.0f : st[2*tid + 1];
        hs[tid] = packh2(h0, h1);
    }
    __syncthreads();

    float2* pbuf2 = (float2*)pbuf;
    float prev_h = 0.0f;
    int   prev_t = -1, prev_sl = 0;

    for (int i = 0; i < TC; ++i) {
        const int sl = dir ? (TC - 1 - i) : i;
        const int t  = t0 + sl;
        const h16* gp = G + (((size_t)dir*TC + sl)*NBATCH + b)*GDIM;

        const unsigned wv = hs[(half << 6) | lane];

        uint4 b0{}, b1{}, b2{};
        if constexpr (STREAM) {
            b0 = Wg4[7*1024 + tid];
            b1 = Wg4[8*1024 + tid];
            b2 = Wg4[9*1024 + tid];
        }
        uint4 l0 = lw4[tid];
        uint4 l1 = lw4[1024 + tid];
        uint4 a0{}, a1{}, a2{};

        float g0 = 0.f, g1 = 0.f, g2 = 0.f, g3 = 0.f;
        if (tid < HDIM) {
            if (prev_t >= 0) {
                if constexpr (V == 0)
                    out[((size_t)b*T_LEN + prev_t)*(2*HDIM) + dir*HDIM + tid] = prev_h;
                else
                    out[((size_t)b*TC + prev_sl)*(2*HDIM) + dir*HDIM + tid] = prev_h;
            }
            g0 = (float)gp[tid];
            g1 = (float)gp[HDIM + tid];
            g2 = (float)gp[2*HDIM + tid];
            g3 = (float)gp[3*HDIM + tid];
        }

        float aA0 = 0.f, aA1 = 0.f, aB0 = 0.f, aB1 = 0.f;
        #pragma unroll
        for (int c = 0; c < 16; ++c) {
            const uint4 wa = (c < 9) ? l0 : a0;
            const uint4 wb = b0;
            b0 = b1; b1 = b2;
            if constexpr (STREAM) { if (c + 3 < 16) b2 = Wg4[(7 + c + 3)*1024 + tid]; }
            if (c < 9) { l0 = l1; if (c + 2 < 9) l1 = lw4[(c + 2)*1024 + tid]; }
            else       { a0 = a1; a1 = a2; }
            if constexpr (STREAM) {
                if (c >= 6 && c < 13) {
                    const uint4 av = Wg4[(c - 6)*1024 + tid];
                    if      (c == 6) a0 = av;
                    else if (c == 7) a1 = av;
                    else             a2 = av;
                }
            }
            if constexpr (DOTS) {
                const unsigned s0 = (unsigned)__builtin_amdgcn_readlane((int)wv, 4*c + 0);
                const unsigned s1 = (unsigned)__builtin_amdgcn_readlane((int)wv, 4*c + 1);
                const unsigned s2 = (unsigned)__builtin_amdgcn_readlane((int)wv, 4*c + 2);
                const unsigned s3 = (unsigned)__builtin_amdgcn_readlane((int)wv, 4*c + 3);
                aA0 = dot2(s0, wa.x, aA0);  aA1 = dot2(s1, wa.y, aA1);
                aA0 = dot2(s2, wa.z, aA0);  aA1 = dot2(s3, wa.w, aA1);
                aB0 = dot2(s0, wb.x, aB0);  aB1 = dot2(s1, wb.y, aB1);
                aB0 = dot2(s2, wb.z, aB0);  aB1 = dot2(s3, wb.w, aB1);
            } else {
                // keep streamed values live without consuming them (anti-DCE, rule #17)
                asm volatile("" :: "v"(wa.x), "v"(wa.w), "v"(wb.x), "v"(wb.w));
            }
        }
        pbuf2[(half << 9) | (q << 6) | lane] = make_float2(aA0 + aA1, aB0 + aB1);
        __syncthreads();

        if (tid < HDIM) {
            const float gi = g0 + pbuf[tid]            + pbuf[GDIM + tid];
            const float gf = g1 + pbuf[HDIM + tid]     + pbuf[GDIM + HDIM + tid];
            const float gg = g2 + pbuf[2*HDIM + tid]   + pbuf[GDIM + 2*HDIM + tid];
            const float go = g3 + pbuf[3*HDIM + tid]   + pbuf[GDIM + 3*HDIM + tid];
            float c2, h2;
            if constexpr (ELEM) {
                c2 = sigm(gf)*cst + sigm(gi)*tanh_safe(gg);
                h2 = sigm(go)*tanh_safe(c2);
            } else {
                c2 = 0.5f*cst + 0.001f*(gf + gi + gg);      // cheap, transcendental-free
                h2 = 0.001f*go + 0.5f*c2;
            }
            hst = 0.1f*hst + 0.9f*h2;
            cst = 0.1f*cst + 0.9f*c2;
            prev_h = fixup(hst, 50.0f);
            prev_t = t;
            prev_sl = sl;
            const float hn = __shfl_xor(hst, 1);
            if ((tid & 1) == 0) hs[tid >> 1] = packh2(hst, hn);
        }
        __syncthreads();
    }

    if (tid < HDIM) {
        if (prev_t >= 0) {
            if constexpr (V == 0)
                out[((size_t)b*T_LEN + prev_t)*(2*HDIM) + dir*HDIM + tid] = prev_h;
            else
                out[((size_t)b*TC + prev_sl)*(2*HDIM) + dir*HDIM + tid] = prev_h;
        }
        st[tid] = hst; st[HDIM + tid] = cst;
    }
}

extern "C" void kernel_launch(void* const* d_in, const int* in_sizes, int n_in,
                              void* d_out, int out_size, void* d_ws, size_t ws_size,
                              hipStream_t stream)
{
    (void)in_sizes; (void)n_in; (void)out_size;
    if (ws_size < 49152000) return;

    const float* x     = (const float*)d_in[0];
    const float* cw0   = (const float*)d_in[1];
    const float* cb0   = (const float*)d_in[2];
    const float* bg0   = (const float*)d_in[3];
    const float* bb0   = (const float*)d_in[4];
    const float* bm0   = (const float*)d_in[5];
    const float* bv0   = (const float*)d_in[6];
    const float* cw1   = (const float*)d_in[7];
    const float* cb1   = (const float*)d_in[8];
    const float* bg1   = (const float*)d_in[9];
    const float* bb1   = (const float*)d_in[10];
    const float* bm1   = (const float*)d_in[11];
    const float* bv1   = (const float*)d_in[12];
    const float* cw2   = (const float*)d_in[13];
    const float* cb2   = (const float*)d_in[14];
    const float* bg2   = (const float*)d_in[15];
    const float* bb2   = (const float*)d_in[16];
    const float* bm2   = (const float*)d_in[17];
    const float* bv2   = (const float*)d_in[18];
    const float* wih_f = (const float*)d_in[19];
    const float* whh_f = (const float*)d_in[20];
    const float* bih_f = (const float*)d_in[21];
    const float* bhh_f = (const float*)d_in[22];
    const float* wih_b = (const float*)d_in[23];
    const float* whh_b = (const float*)d_in[24];
    const float* bih_b = (const float*)d_in[25];
    const float* bhh_b = (const float*)d_in[26];

    char* ws = (char*)d_ws;
    char* od = (char*)d_out;
    h16*      A   = (h16*)(ws);
    h16*      G   = (h16*)(ws + 32768000);
    float*    st  = (float*)(ws + 45875200);
    unsigned* W16 = (unsigned*)(ws + 46006272);
    h16*      Wg  = (h16*)(ws + 47054848);
    h16*      Bd  = (h16*)(od);
    h16*      Wp0 = (h16*)(od + 36000000);
    h16*      Wp1 = (h16*)(od + 36409600);
    h16*      Wp2 = (h16*)(od + 41652480);
    h16*      Xt0 = (h16*)(od + 46895360);
    float*    out = (float*)d_out;

    // packs
    pack_convw_kernel<<<dim3((5*512*80  + 255)/256), 256, 0, stream>>>(cw0, Wp0, 80);
    pack_convw_kernel<<<dim3((5*512*512 + 255)/256), 256, 0, stream>>>(cw1, Wp1, 512);
    pack_convw_kernel<<<dim3((5*512*512 + 255)/256), 256, 0, stream>>>(cw2, Wp2, 512);
    pack_wih_kernel<<<dim3(2*1024*512/256), 256, 0, stream>>>(wih_f, wih_b, Wg);
    whh_prep_kernel<<<dim3(1024), 256, 0, stream>>>(whh_f, whh_b, W16);
    x0_transpose_kernel<<<dim3(4, 32), 256, 0, stream>>>(x, Xt0);

    // convs (implicit-GEMM MFMA)
    const dim3 cgrid(8, 4, 32);
    conv_mfma_kernel<<<cgrid, 512, 0, stream>>>(Xt0, Wp0, A,  cb0, bg0, bb0, bm0, bv0, 80);
    conv_mfma_kernel<<<cgrid, 512, 0, stream>>>(A,   Wp1, Bd, cb1, bg1, bb1, bm1, bv1, 512);
    conv_mfma_kernel<<<cgrid, 512, 0, stream>>>(Bd,  Wp2, A,  cb2, bg2, bb2, bm2, bv2, 512);

    for (int c = 0; c < T_LEN / TC; ++c) {
        const int t0f = c * TC;
        const int t0b = (T_LEN - TC) - c * TC;
        gates_mfma_kernel<<<dim3(2, 8, 64), 256, 0, stream>>>(A, Wg, bih_f, bhh_f, bih_b, bhh_b, G, t0f, t0b);
        lstm_chunk_kernel<0><<<dim3(64), 1024, 0, stream>>>(G, W16, st, out, t0f, t0b, c == 0);
    }

    // ---- ablation probes (after production; write only dead ws scratch; deterministic) ----
    float* pout = (float*)(ws);              // A region, dead after last gates_mfma (6.6MB used)
    float* pst  = (float*)(ws + 20000000);   // inside A region, past pout
    lstm_chunk_kernel<1><<<dim3(64), 1024, 0, stream>>>(G, W16, pst, pout, 0, 0, 1);  // no-stream
    lstm_chunk_kernel<2><<<dim3(64), 1024, 0, stream>>>(G, W16, pst, pout, 0, 0, 1);  // no-dots
    lstm_chunk_kernel<3><<<dim3(64), 1024, 0, stream>>>(G, W16, pst, pout, 0, 0, 1);  // cheap-elem
    lstm_chunk_kernel<4><<<dim3(64), 1024, 0, stream>>>(G, W16, pst, pout, 0, 0, 1);  // skeleton
}

// Round 18
// 1769.953 us; speedup vs baseline: 2.3116x; 1.8527x over previous
//
#include <hip/hip_runtime.h>

// Encoder: 3x [conv1d(K=5,pad2)+BN+ReLU] -> biLSTM(H=256) zoneout(0.1).  MFMA convs/gates; VALU recurrence.
// r18 lstm: INT8 recurrence weights (per-row scale) + int8 h + v_dot4_i32_i8.
//   r17 ablation: V0 moves 368KB/CU/step = 73.6 B/cyc = per-CU L2 port ceiling -> byte-bound.
//   int8 halves weight bytes: 256B/thread = 16 uint4 -> 9 in LDS (144KB) + 7 streamed (112KB/step).
// ws:    A f16 @0 (32,768,000) | G f16 [2][100][32][1024] @32,768,000 (13,107,200)
//        | state @45,875,200 (131,072) | W8 @46,006,272 (524,288) | scl f32[2048] @46,530,560 (8,192)
//        | Wg f16 [2][1024][512] @47,054,848 (2,097,152) -> 49,152,000 B
// d_out: Bd (conv1 out) @0 | Wp0 @36,000,000 | Wp1 @36,409,600 | Wp2 @41,652,480 | Xt0 @46,895,360

#define T_LEN 1000
#define NBATCH 32
#define CCH 512
#define HDIM 256
#define GDIM 1024
#define TC 100

typedef _Float16 h16;
typedef _Float16 h16x2 __attribute__((ext_vector_type(2)));
typedef _Float16 f16x8 __attribute__((ext_vector_type(8)));
typedef float    f32x4 __attribute__((ext_vector_type(4)));

__device__ __forceinline__ float fixup(float v, float alt){
    union { float f; unsigned u; } c; c.f = v;
    return ((c.u & 0x7f800000u) == 0x7f800000u) ? alt : v;
}
__device__ __forceinline__ float clamp_s(float v, float lo, float hi){
    return fminf(fmaxf(v, lo), hi);
}
__device__ __forceinline__ float sigm(float x){
    const float xc = clamp_s(x, -30.f, 30.f);
    return 1.0f / (1.0f + __expf(-xc));
}
__device__ __forceinline__ float tanh_safe(float x){
    const float ax = fminf(fabsf(x), 30.0f);
    const float t  = __expf(-2.0f * ax);
    const float r  = (1.0f - t) / (1.0f + t);
    return copysignf(r, x);
}
__device__ __forceinline__ unsigned packh2(float x, float y){
    union Cv { unsigned u; h16 h[2]; };
    Cv c; c.h[0] = (h16)x; c.h[1] = (h16)y;
    return c.u;
}
// v_dot4_i32_i8: 4 int8 MACs + i32 accumulate
__device__ __forceinline__ int dot4i8(int a, int b, int c){
#if defined(__has_builtin) && __has_builtin(__builtin_amdgcn_sdot4)
    return __builtin_amdgcn_sdot4(a, b, c, false);
#else
    int r = c;
    #pragma unroll
    for (int k = 0; k < 4; ++k) {
        const int av = (a << (24 - 8*k)) >> 24;
        const int bv = (b << (24 - 8*k)) >> 24;
        r += av * bv;
    }
    return r;
#endif
}

// ---------------- packs ----------------
__global__ __launch_bounds__(256)
void pack_convw_kernel(const float* __restrict__ cw, h16* __restrict__ Wp, int cin)
{
    const int n = blockIdx.x*256 + threadIdx.x;
    if (n >= 5*512*cin) return;
    const int k   = n / (512*cin);
    const int rem = n - k*512*cin;
    const int co  = rem / cin;
    const int ci  = rem - co*cin;
    Wp[n] = (h16)cw[((size_t)co*cin + ci)*5 + k];
}

__global__ __launch_bounds__(256)
void pack_wih_kernel(const float* __restrict__ wf, const float* __restrict__ wb, h16* __restrict__ Wg)
{
    const int n = blockIdx.x*256 + threadIdx.x;
    const float* src = (n < 1024*512) ? wf : wb;
    Wg[n] = (h16)src[n & (1024*512 - 1)];
}

// per-row |max| -> dot-scale scl[dir*1024+row] = max/(127*127)
__global__ __launch_bounds__(256)
void whh_scale_kernel(const float* __restrict__ whh_f, const float* __restrict__ whh_b,
                      float* __restrict__ scl)
{
    const int n = blockIdx.x*256 + threadIdx.x;   // 2048
    if (n >= 2048) return;
    const float* whh = (n >= 1024) ? whh_b : whh_f;
    const int row = n & 1023;
    float m = 0.f;
    for (int k = 0; k < HDIM; ++k) m = fmaxf(m, fabsf(whh[(size_t)row*HDIM + k]));
    scl[n] = fmaxf(m, 1e-8f) / 16129.0f;
}

// whh f32 -> int8 chunk-major pack. Thread t: half=(t>>6)&1, q=t>>7, l=t&63; rA=q*128+2l, rB=rA+1;
// k-base = 128*half. uint4 = 16 int8 = k-group g (16 consecutive k). Chunks (u32 n = dir*65536+chunk*4096+t*4+e):
//   chunk 0..6  (stream): row=rB, g=chunk+1 | chunk 7..14 (LDS): row=rA, g=chunk-7 | chunk 15 (LDS): row=rB, g=0
__global__ __launch_bounds__(256)
void whh_prep_kernel(const float* __restrict__ whh_f, const float* __restrict__ whh_b,
                     const float* __restrict__ scl, unsigned* __restrict__ W8)
{
    const int n = blockIdx.x * 256 + threadIdx.x;   // 131072 u32
    if (n >= 2*16*1024*4) return;
    const int dir   = n >> 16;
    const int rem   = n & 65535;
    const int chunk = rem >> 12;
    const int idx   = rem & 4095;
    const int t     = idx >> 2;
    const int e     = idx & 3;
    const float* whh = dir ? whh_b : whh_f;
    const int half = (t >> 6) & 1;
    const int qq   = t >> 7;
    const int l    = t & 63;
    const int rA   = qq*128 + 2*l;
    int row, g;
    if (chunk < 7)       { row = rA + 1; g = chunk + 1; }
    else if (chunk < 15) { row = rA;     g = chunk - 7; }
    else                 { row = rA + 1; g = 0; }
    const float inv = 1.0f / (scl[dir*1024 + row] * 127.0f);   // = 127/max
    const int k0 = 128*half + 16*g + 4*e;
    unsigned u = 0;
    #pragma unroll
    for (int j = 0; j < 4; ++j) {
        const float w = whh[(size_t)row*HDIM + k0 + j];
        int qv = (int)rintf(w * inv);
        qv = qv > 127 ? 127 : (qv < -127 ? -127 : qv);
        u |= ((unsigned)(qv & 0xFF)) << (8*j);
    }
    W8[n] = u;
}

__global__ __launch_bounds__(256)
void x0_transpose_kernel(const float* __restrict__ x, h16* __restrict__ Xt0)
{
    const int b = blockIdx.y;
    const int t = blockIdx.x*256 + threadIdx.x;
    if (t >= T_LEN) return;
    h16 v[80];
    #pragma unroll
    for (int c = 0; c < 80; ++c) v[c] = (h16)x[((size_t)b*80 + c)*T_LEN + t];
    #pragma unroll
    for (int g = 0; g < 10; ++g)
        *(f16x8*)(Xt0 + ((size_t)b*T_LEN + t)*80 + g*8) = *(const f16x8*)(v + g*8);
}

// ---------------- conv (implicit GEMM, MFMA 16x16x32 f16) ----------------
__global__ __attribute__((amdgpu_flat_work_group_size(512,512), amdgpu_waves_per_eu(4,4)))
void conv_mfma_kernel(const h16* __restrict__ Xt, const h16* __restrict__ Wp,
                      h16* __restrict__ outp,
                      const float* __restrict__ cb, const float* __restrict__ bg,
                      const float* __restrict__ bb, const float* __restrict__ bm,
                      const float* __restrict__ bv, int cin)
{
    const int t0   = blockIdx.x * 128;
    const int co0  = blockIdx.y * 128;
    const int b    = blockIdx.z;
    const int tid  = threadIdx.x;
    const int lane = tid & 63;
    const int w    = tid >> 6;
    const int wm   = w >> 2;
    const int wn   = w & 3;
    const int lr   = lane & 15;
    const int lg   = lane >> 4;

    __shared__ __align__(16) h16 Xs[132*40];
    __shared__ __align__(16) h16 Ws[5*128*40];

    f32x4 acc[4][2];
    #pragma unroll
    for (int m = 0; m < 4; ++m)
        #pragma unroll
        for (int n = 0; n < 2; ++n)
            #pragma unroll
            for (int r = 0; r < 4; ++r) acc[m][n][r] = 0.f;

    const int ksteps = (cin + 31) >> 5;
    for (int cs = 0; cs < ksteps; ++cs) {
        const int c0 = cs << 5;
        for (int id = tid; id < 132*4; id += 512) {
            const int row = id >> 2, g = id & 3;
            const int t = t0 + row - 2;
            f16x8 v;
            #pragma unroll
            for (int j = 0; j < 8; ++j) v[j] = (h16)0.f;
            if (t >= 0 && t < T_LEN) {
                const int c = c0 + g*8;
                if (c + 8 <= cin) {
                    v = *(const f16x8*)(Xt + ((size_t)b*T_LEN + t)*cin + c);
                } else if (c < cin) {
                    #pragma unroll
                    for (int j = 0; j < 8; ++j) if (c + j < cin) v[j] = Xt[((size_t)b*T_LEN + t)*cin + c + j];
                }
            }
            *(f16x8*)(Xs + row*40 + g*8) = v;
        }
        for (int id = tid; id < 5*128*4; id += 512) {
            const int k  = id >> 9;
            const int co = (id >> 2) & 127;
            const int g  = id & 3;
            const int c  = c0 + g*8;
            f16x8 v;
            #pragma unroll
            for (int j = 0; j < 8; ++j) v[j] = (h16)0.f;
            if (c + 8 <= cin) {
                v = *(const f16x8*)(Wp + ((size_t)k*512 + co0 + co)*cin + c);
            } else if (c < cin) {
                #pragma unroll
                for (int j = 0; j < 8; ++j) if (c + j < cin) v[j] = Wp[((size_t)k*512 + co0 + co)*cin + c + j];
            }
            *(f16x8*)(Ws + (k*128 + co)*40 + g*8) = v;
        }
        __syncthreads();

        #pragma unroll
        for (int k = 0; k < 5; ++k) {
            const f16x8 b0 = *(const f16x8*)(Ws + (k*128 + wn*32 +      lr)*40 + lg*8);
            const f16x8 b1 = *(const f16x8*)(Ws + (k*128 + wn*32 + 16 + lr)*40 + lg*8);
            #pragma unroll
            for (int m = 0; m < 4; ++m) {
                const f16x8 a = *(const f16x8*)(Xs + (wm*64 + m*16 + lr + k)*40 + lg*8);
                acc[m][0] = __builtin_amdgcn_mfma_f32_16x16x32_f16(a, b0, acc[m][0], 0, 0, 0);
                acc[m][1] = __builtin_amdgcn_mfma_f32_16x16x32_f16(a, b1, acc[m][1], 0, 0, 0);
            }
        }
        __syncthreads();
    }

    #pragma unroll
    for (int nf = 0; nf < 2; ++nf) {
        const int co = co0 + wn*32 + nf*16 + lr;
        const float s  = bg[co] * rsqrtf(fmaxf(bv[co] + 1e-5f, 1e-8f));
        const float sh = (cb[co] - bm[co]) * s + bb[co];
        #pragma unroll
        for (int m = 0; m < 4; ++m) {
            #pragma unroll
            for (int r = 0; r < 4; ++r) {
                const int t = t0 + wm*64 + m*16 + lg*4 + r;
                if (t < T_LEN) {
                    const float y = fixup(clamp_s(fmaxf(acc[m][nf][r]*s + sh, 0.f), 0.f, 60000.f), 0.f);
                    outp[((size_t)b*T_LEN + t)*CCH + co] = (h16)y;
                }
            }
        }
    }
}

// ---------------- gates GEMM (MFMA), one time-chunk, both dirs ----------------
__global__ __attribute__((amdgpu_flat_work_group_size(256,256), amdgpu_waves_per_eu(4,4)))
void gates_mfma_kernel(const h16* __restrict__ Xt,
                       const h16* __restrict__ Wg,
                       const float* __restrict__ bih_f, const float* __restrict__ bhh_f,
                       const float* __restrict__ bih_b, const float* __restrict__ bhh_b,
                       h16* __restrict__ G, int t0f, int t0b)
{
    const int tt   = blockIdx.x;
    const int r0   = blockIdx.y * 128;
    const int b    = blockIdx.z & 31;
    const int dir  = blockIdx.z >> 5;
    const int t0c  = dir ? t0b : t0f;
    const int tid  = threadIdx.x;
    const int lane = tid & 63;
    const int w    = tid >> 6;
    const int lr   = lane & 15;
    const int lg   = lane >> 4;
    const float* bi = dir ? bih_b : bih_f;
    const float* bh = dir ? bhh_b : bhh_f;
    const h16* Wd = Wg + (size_t)dir*1024*512;

    __shared__ __align__(16) h16 Xs[64*40];
    __shared__ __align__(16) h16 Ws[128*40];

    f32x4 acc[4][2];
    #pragma unroll
    for (int m = 0; m < 4; ++m)
        #pragma unroll
        for (int n = 0; n < 2; ++n)
            #pragma unroll
            for (int r = 0; r < 4; ++r) acc[m][n][r] = 0.f;

    for (int cs = 0; cs < 16; ++cs) {
        const int c0 = cs << 5;
        for (int id = tid; id < 64*4; id += 256) {
            const int row = id >> 2, g = id & 3;
            int t = t0c + tt*64 + row; if (t >= T_LEN) t = T_LEN - 1;
            *(f16x8*)(Xs + row*40 + g*8) = *(const f16x8*)(Xt + ((size_t)b*T_LEN + t)*CCH + c0 + g*8);
        }
        for (int id = tid; id < 128*4; id += 256) {
            const int row = id >> 2, g = id & 3;
            *(f16x8*)(Ws + row*40 + g*8) = *(const f16x8*)(Wd + (size_t)(r0 + row)*CCH + c0 + g*8);
        }
        __syncthreads();

        const f16x8 b0 = *(const f16x8*)(Ws + (w*32 +      lr)*40 + lg*8);
        const f16x8 b1 = *(const f16x8*)(Ws + (w*32 + 16 + lr)*40 + lg*8);
        #pragma unroll
        for (int m = 0; m < 4; ++m) {
            const f16x8 a = *(const f16x8*)(Xs + (m*16 + lr)*40 + lg*8);
            acc[m][0] = __builtin_amdgcn_mfma_f32_16x16x32_f16(a, b0, acc[m][0], 0, 0, 0);
            acc[m][1] = __builtin_amdgcn_mfma_f32_16x16x32_f16(a, b1, acc[m][1], 0, 0, 0);
        }
        __syncthreads();
    }

    #pragma unroll
    for (int nf = 0; nf < 2; ++nf) {
        const int row = r0 + w*32 + nf*16 + lr;
        const float bias = bi[row] + bh[row];
        #pragma unroll
        for (int m = 0; m < 4; ++m) {
            #pragma unroll
            for (int r = 0; r < 4; ++r) {
                const int tl = tt*64 + m*16 + lg*4 + r;
                if (tl < TC)
                    G[(((size_t)dir*TC + tl)*NBATCH + b)*GDIM + row]
                        = (h16)fixup(clamp_s(acc[m][nf][r] + bias, -60000.f, 60000.f), 0.f);
            }
        }
    }
}

// ---------------- persistent biLSTM recurrence: INT8 weights + int8 h + dot4 ----------------
// Thread t: half=(t>>6)&1 (k-half), q=t>>7, l=t&63; rows rA=q*128+2l, rB=rA+1.
// Weights 16 uint4/thread: LDS slots 0..7 = rowA g0..7, slot 8 = rowB g0; stream chunks 0..6 = rowB g1..7.
// h int8 in hq8[256] (LDS); wave gets its k-half as 32 u32 via 1 ds_read + 32 readlane.
__global__ __attribute__((amdgpu_flat_work_group_size(1024, 1024), amdgpu_waves_per_eu(4, 4)))
void lstm_chunk_kernel(const h16* __restrict__ G,
                       const unsigned* __restrict__ W8,
                       const float* __restrict__ scl,
                       float* __restrict__ state,
                       float* __restrict__ out,
                       int t0f, int t0b, int first)
{
    const int tid  = threadIdx.x;
    const int lane = tid & 63;
    const int half = (tid >> 6) & 1;
    const int q    = tid >> 7;
    const int dir  = blockIdx.x >> 5;
    const int b    = blockIdx.x & 31;
    const int t0   = dir ? t0b : t0f;
    float* st = state + ((size_t)(dir*NBATCH + b))*2*HDIM;
    const uint4* Wg8 = (const uint4*)W8 + (size_t)dir*16384;   // 16 chunks x 1024 uint4
    const uint4* Wl8 = Wg8 + 7*1024;                            // LDS source: chunks 7..15

    __shared__ __align__(16) uint4 lw8[9*1024];        // 144 KB
    __shared__ __align__(4)  unsigned char hq8[256];   // h int8
    __shared__ float pbuf[2*GDIM];                     // 8 KB

    #pragma unroll
    for (int s = 0; s < 9; ++s)
        lw8[s*1024 + tid] = Wl8[s*1024 + tid];

    const int rA = q*128 + 2*lane;
    const float sclA = scl[dir*1024 + rA];
    const float sclB = scl[dir*1024 + rA + 1];

    float hst = 0.0f, cst = 0.0f;
    if (tid < HDIM) {
        if (!first) { hst = st[tid]; cst = st[HDIM + tid]; }
        const int qh = (int)rintf(clamp_s(hst, -1.f, 1.f) * 127.f);
        hq8[tid] = (unsigned char)(qh & 0xFF);
    }
    __syncthreads();

    float2* pbuf2 = (float2*)pbuf;
    float prev_h = 0.0f;
    int   prev_t = -1;

    for (int i = 0; i < TC; ++i) {
        const int sl = dir ? (TC - 1 - i) : i;
        const int t  = t0 + sl;
        const h16* gp = G + (((size_t)dir*TC + sl)*NBATCH + b)*GDIM;

        const unsigned wv = ((const unsigned*)hq8)[(half << 5) | (lane & 31)];

        // stream: 7 uint4 (rowB g1..7) all issued up-front; consumed after rowA dots
        const uint4 sb0 = Wg8[0*1024 + tid];
        const uint4 sb1 = Wg8[1*1024 + tid];
        const uint4 sb2 = Wg8[2*1024 + tid];
        const uint4 sb3 = Wg8[3*1024 + tid];
        const uint4 sb4 = Wg8[4*1024 + tid];
        const uint4 sb5 = Wg8[5*1024 + tid];
        const uint4 sb6 = Wg8[6*1024 + tid];

        float g0 = 0.f, g1 = 0.f, g2 = 0.f, g3 = 0.f;
        if (tid < HDIM) {
            if (prev_t >= 0)
                out[((size_t)b*T_LEN + prev_t)*(2*HDIM) + dir*HDIM + tid] = prev_h;
            g0 = (float)gp[tid];
            g1 = (float)gp[HDIM + tid];
            g2 = (float)gp[2*HDIM + tid];
            g3 = (float)gp[3*HDIM + tid];
        }

        // h k-half broadcast: s[j] = u32 of 4 int8 h (units 128*half + 4j ..+3)
        int s[32];
        #pragma unroll
        for (int j = 0; j < 32; ++j)
            s[j] = __builtin_amdgcn_readlane((int)wv, j);

        int accA = 0, accB = 0;
        #pragma unroll
        for (int g = 0; g < 8; ++g) {                   // rowA from LDS
            const uint4 wA = lw8[g*1024 + tid];
            accA = dot4i8(s[4*g + 0], (int)wA.x, accA);
            accA = dot4i8(s[4*g + 1], (int)wA.y, accA);
            accA = dot4i8(s[4*g + 2], (int)wA.z, accA);
            accA = dot4i8(s[4*g + 3], (int)wA.w, accA);
        }
        {                                               // rowB g0 from LDS slot 8
            const uint4 w0 = lw8[8*1024 + tid];
            accB = dot4i8(s[0], (int)w0.x, accB);
            accB = dot4i8(s[1], (int)w0.y, accB);
            accB = dot4i8(s[2], (int)w0.z, accB);
            accB = dot4i8(s[3], (int)w0.w, accB);
        }
        #define ROWB(G_, V_) \
            accB = dot4i8(s[4*(G_) + 0], (int)(V_).x, accB); \
            accB = dot4i8(s[4*(G_) + 1], (int)(V_).y, accB); \
            accB = dot4i8(s[4*(G_) + 2], (int)(V_).z, accB); \
            accB = dot4i8(s[4*(G_) + 3], (int)(V_).w, accB);
        ROWB(1, sb0) ROWB(2, sb1) ROWB(3, sb2) ROWB(4, sb3)
        ROWB(5, sb4) ROWB(6, sb5) ROWB(7, sb6)
        #undef ROWB

        pbuf2[(half << 9) | (q << 6) | lane] = make_float2((float)accA * sclA, (float)accB * sclB);
        __syncthreads();

        if (tid < HDIM) {
            const float gi = g0 + pbuf[tid]            + pbuf[GDIM + tid];
            const float gf = g1 + pbuf[HDIM + tid]     + pbuf[GDIM + HDIM + tid];
            const float gg = g2 + pbuf[2*HDIM + tid]   + pbuf[GDIM + 2*HDIM + tid];
            const float go = g3 + pbuf[3*HDIM + tid]   + pbuf[GDIM + 3*HDIM + tid];
            const float c2 = sigm(gf)*cst + sigm(gi)*tanh_safe(gg);
            const float h2 = sigm(go)*tanh_safe(c2);
            hst = 0.1f*hst + 0.9f*h2;                   // zoneout (output is post-zoneout h)
            cst = 0.1f*cst + 0.9f*c2;
            prev_h = fixup(hst, 50.0f);
            prev_t = t;
            const int qh = (int)rintf(clamp_s(hst, -1.f, 1.f) * 127.f);
            hq8[tid] = (unsigned char)(qh & 0xFF);      // next step's recurrent h (int8)
        }
        __syncthreads();
    }

    if (tid < HDIM) {
        if (prev_t >= 0)
            out[((size_t)b*T_LEN + prev_t)*(2*HDIM) + dir*HDIM + tid] = prev_h;
        st[tid] = hst; st[HDIM + tid] = cst;
    }
}

extern "C" void kernel_launch(void* const* d_in, const int* in_sizes, int n_in,
                              void* d_out, int out_size, void* d_ws, size_t ws_size,
                              hipStream_t stream)
{
    (void)in_sizes; (void)n_in; (void)out_size;
    if (ws_size < 49152000) return;

    const float* x     = (const float*)d_in[0];
    const float* cw0   = (const float*)d_in[1];
    const float* cb0   = (const float*)d_in[2];
    const float* bg0   = (const float*)d_in[3];
    const float* bb0   = (const float*)d_in[4];
    const float* bm0   = (const float*)d_in[5];
    const float* bv0   = (const float*)d_in[6];
    const float* cw1   = (const float*)d_in[7];
    const float* cb1   = (const float*)d_in[8];
    const float* bg1   = (const float*)d_in[9];
    const float* bb1   = (const float*)d_in[10];
    const float* bm1   = (const float*)d_in[11];
    const float* bv1   = (const float*)d_in[12];
    const float* cw2   = (const float*)d_in[13];
    const float* cb2   = (const float*)d_in[14];
    const float* bg2   = (const float*)d_in[15];
    const float* bb2   = (const float*)d_in[16];
    const float* bm2   = (const float*)d_in[17];
    const float* bv2   = (const float*)d_in[18];
    const float* wih_f = (const float*)d_in[19];
    const float* whh_f = (const float*)d_in[20];
    const float* bih_f = (const float*)d_in[21];
    const float* bhh_f = (const float*)d_in[22];
    const float* wih_b = (const float*)d_in[23];
    const float* whh_b = (const float*)d_in[24];
    const float* bih_b = (const float*)d_in[25];
    const float* bhh_b = (const float*)d_in[26];

    char* ws = (char*)d_ws;
    char* od = (char*)d_out;
    h16*      A   = (h16*)(ws);
    h16*      G   = (h16*)(ws + 32768000);
    float*    st  = (float*)(ws + 45875200);
    unsigned* W8  = (unsigned*)(ws + 46006272);
    float*    scl = (float*)(ws + 46530560);
    h16*      Wg  = (h16*)(ws + 47054848);
    h16*      Bd  = (h16*)(od);
    h16*      Wp0 = (h16*)(od + 36000000);
    h16*      Wp1 = (h16*)(od + 36409600);
    h16*      Wp2 = (h16*)(od + 41652480);
    h16*      Xt0 = (h16*)(od + 46895360);
    float*    out = (float*)d_out;

    // packs
    pack_convw_kernel<<<dim3((5*512*80  + 255)/256), 256, 0, stream>>>(cw0, Wp0, 80);
    pack_convw_kernel<<<dim3((5*512*512 + 255)/256), 256, 0, stream>>>(cw1, Wp1, 512);
    pack_convw_kernel<<<dim3((5*512*512 + 255)/256), 256, 0, stream>>>(cw2, Wp2, 512);
    pack_wih_kernel<<<dim3(2*1024*512/256), 256, 0, stream>>>(wih_f, wih_b, Wg);
    whh_scale_kernel<<<dim3(8), 256, 0, stream>>>(whh_f, whh_b, scl);
    whh_prep_kernel<<<dim3(512), 256, 0, stream>>>(whh_f, whh_b, scl, W8);
    x0_transpose_kernel<<<dim3(4, 32), 256, 0, stream>>>(x, Xt0);

    // convs (implicit-GEMM MFMA)
    const dim3 cgrid(8, 4, 32);
    conv_mfma_kernel<<<cgrid, 512, 0, stream>>>(Xt0, Wp0, A,  cb0, bg0, bb0, bm0, bv0, 80);
    conv_mfma_kernel<<<cgrid, 512, 0, stream>>>(A,   Wp1, Bd, cb1, bg1, bb1, bm1, bv1, 512);
    conv_mfma_kernel<<<cgrid, 512, 0, stream>>>(Bd,  Wp2, A,  cb2, bg2, bb2, bm2, bv2, 512);

    for (int c = 0; c < T_LEN / TC; ++c) {
        const int t0f = c * TC;
        const int t0b = (T_LEN - TC) - c * TC;
        gates_mfma_kernel<<<dim3(2, 8, 64), 256, 0, stream>>>(A, Wg, bih_f, bhh_f, bih_b, bhh_b, G, t0f, t0b);
        lstm_chunk_kernel<<<dim3(64), 1024, 0, stream>>>(G, W8, scl, st, out, t0f, t0b, c == 0);
    }
}

// Round 19
// 1730.871 us; speedup vs baseline: 2.3638x; 1.0226x over previous
//
#include <hip/hip_runtime.h>

// Encoder: 3x [conv1d(K=5,pad2)+BN+ReLU] -> biLSTM(H=256) zoneout(0.1).  MFMA convs/gates; VALU recurrence.
// r19 lstm: int8 weights fully RESIDENT -- 9 uint4/thread hoisted into registers (loop-invariant,
//   rowB g0..7 + rowA g7) + 7 chunks in LDS (rowA g0..6, 112 KB). LDS reads/step 9->7 b128.
//   Math bit-identical to r18 (same accumulation order g0..g7 per row).
// ws:    A f16 @0 (32,768,000) | G f16 [2][100][32][1024] @32,768,000 (13,107,200)
//        | state @45,875,200 (131,072) | W8 @46,006,272 (524,288) | scl f32[2048] @46,530,560 (8,192)
//        | Wg f16 [2][1024][512] @47,054,848 (2,097,152) -> 49,152,000 B
// d_out: Bd (conv1 out) @0 | Wp0 @36,000,000 | Wp1 @36,409,600 | Wp2 @41,652,480 | Xt0 @46,895,360

#define T_LEN 1000
#define NBATCH 32
#define CCH 512
#define HDIM 256
#define GDIM 1024
#define TC 100

typedef _Float16 h16;
typedef _Float16 h16x2 __attribute__((ext_vector_type(2)));
typedef _Float16 f16x8 __attribute__((ext_vector_type(8)));
typedef float    f32x4 __attribute__((ext_vector_type(4)));

__device__ __forceinline__ float fixup(float v, float alt){
    union { float f; unsigned u; } c; c.f = v;
    return ((c.u & 0x7f800000u) == 0x7f800000u) ? alt : v;
}
__device__ __forceinline__ float clamp_s(float v, float lo, float hi){
    return fminf(fmaxf(v, lo), hi);
}
__device__ __forceinline__ float sigm(float x){
    const float xc = clamp_s(x, -30.f, 30.f);
    return 1.0f / (1.0f + __expf(-xc));
}
__device__ __forceinline__ float tanh_safe(float x){
    const float ax = fminf(fabsf(x), 30.0f);
    const float t  = __expf(-2.0f * ax);
    const float r  = (1.0f - t) / (1.0f + t);
    return copysignf(r, x);
}
// v_dot4_i32_i8: 4 int8 MACs + i32 accumulate
__device__ __forceinline__ int dot4i8(int a, int b, int c){
#if defined(__has_builtin) && __has_builtin(__builtin_amdgcn_sdot4)
    return __builtin_amdgcn_sdot4(a, b, c, false);
#else
    int r = c;
    #pragma unroll
    for (int k = 0; k < 4; ++k) {
        const int av = (a << (24 - 8*k)) >> 24;
        const int bv = (b << (24 - 8*k)) >> 24;
        r += av * bv;
    }
    return r;
#endif
}

// ---------------- packs ----------------
__global__ __launch_bounds__(256)
void pack_convw_kernel(const float* __restrict__ cw, h16* __restrict__ Wp, int cin)
{
    const int n = blockIdx.x*256 + threadIdx.x;
    if (n >= 5*512*cin) return;
    const int k   = n / (512*cin);
    const int rem = n - k*512*cin;
    const int co  = rem / cin;
    const int ci  = rem - co*cin;
    Wp[n] = (h16)cw[((size_t)co*cin + ci)*5 + k];
}

__global__ __launch_bounds__(256)
void pack_wih_kernel(const float* __restrict__ wf, const float* __restrict__ wb, h16* __restrict__ Wg)
{
    const int n = blockIdx.x*256 + threadIdx.x;
    const float* src = (n < 1024*512) ? wf : wb;
    Wg[n] = (h16)src[n & (1024*512 - 1)];
}

// per-row |max| -> dot-scale scl[dir*1024+row] = max/(127*127)
__global__ __launch_bounds__(256)
void whh_scale_kernel(const float* __restrict__ whh_f, const float* __restrict__ whh_b,
                      float* __restrict__ scl)
{
    const int n = blockIdx.x*256 + threadIdx.x;   // 2048
    if (n >= 2048) return;
    const float* whh = (n >= 1024) ? whh_b : whh_f;
    const int row = n & 1023;
    float m = 0.f;
    for (int k = 0; k < HDIM; ++k) m = fmaxf(m, fabsf(whh[(size_t)row*HDIM + k]));
    scl[n] = fmaxf(m, 1e-8f) / 16129.0f;
}

// whh f32 -> int8 chunk-major pack (r19 mapping). Thread t: half=(t>>6)&1, q=t>>7, l=t&63;
// rA=q*128+2l, rB=rA+1; k-base=128*half; uint4 = 16 int8 = k-group g.
// Chunks (u32 n = dir*65536 + chunk*4096 + t*4 + e):
//   chunk 0..7  (REGS): row=rB, g=chunk | chunk 8 (REGS): row=rA, g=7 | chunk 9..15 (LDS): row=rA, g=chunk-9
__global__ __launch_bounds__(256)
void whh_prep_kernel(const float* __restrict__ whh_f, const float* __restrict__ whh_b,
                     const float* __restrict__ scl, unsigned* __restrict__ W8)
{
    const int n = blockIdx.x * 256 + threadIdx.x;   // 131072 u32
    if (n >= 2*16*1024*4) return;
    const int dir   = n >> 16;
    const int rem   = n & 65535;
    const int chunk = rem >> 12;
    const int idx   = rem & 4095;
    const int t     = idx >> 2;
    const int e     = idx & 3;
    const float* whh = dir ? whh_b : whh_f;
    const int half = (t >> 6) & 1;
    const int qq   = t >> 7;
    const int l    = t & 63;
    const int rA   = qq*128 + 2*l;
    int row, g;
    if (chunk < 8)       { row = rA + 1; g = chunk; }
    else if (chunk == 8) { row = rA;     g = 7; }
    else                 { row = rA;     g = chunk - 9; }
    const float inv = 1.0f / (scl[dir*1024 + row] * 127.0f);   // = 127/max
    const int k0 = 128*half + 16*g + 4*e;
    unsigned u = 0;
    #pragma unroll
    for (int j = 0; j < 4; ++j) {
        const float w = whh[(size_t)row*HDIM + k0 + j];
        int qv = (int)rintf(w * inv);
        qv = qv > 127 ? 127 : (qv < -127 ? -127 : qv);
        u |= ((unsigned)(qv & 0xFF)) << (8*j);
    }
    W8[n] = u;
}

__global__ __launch_bounds__(256)
void x0_transpose_kernel(const float* __restrict__ x, h16* __restrict__ Xt0)
{
    const int b = blockIdx.y;
    const int t = blockIdx.x*256 + threadIdx.x;
    if (t >= T_LEN) return;
    h16 v[80];
    #pragma unroll
    for (int c = 0; c < 80; ++c) v[c] = (h16)x[((size_t)b*80 + c)*T_LEN + t];
    #pragma unroll
    for (int g = 0; g < 10; ++g)
        *(f16x8*)(Xt0 + ((size_t)b*T_LEN + t)*80 + g*8) = *(const f16x8*)(v + g*8);
}

// ---------------- conv (implicit GEMM, MFMA 16x16x32 f16) ----------------
__global__ __attribute__((amdgpu_flat_work_group_size(512,512), amdgpu_waves_per_eu(4,4)))
void conv_mfma_kernel(const h16* __restrict__ Xt, const h16* __restrict__ Wp,
                      h16* __restrict__ outp,
                      const float* __restrict__ cb, const float* __restrict__ bg,
                      const float* __restrict__ bb, const float* __restrict__ bm,
                      const float* __restrict__ bv, int cin)
{
    const int t0   = blockIdx.x * 128;
    const int co0  = blockIdx.y * 128;
    const int b    = blockIdx.z;
    const int tid  = threadIdx.x;
    const int lane = tid & 63;
    const int w    = tid >> 6;
    const int wm   = w >> 2;
    const int wn   = w & 3;
    const int lr   = lane & 15;
    const int lg   = lane >> 4;

    __shared__ __align__(16) h16 Xs[132*40];
    __shared__ __align__(16) h16 Ws[5*128*40];

    f32x4 acc[4][2];
    #pragma unroll
    for (int m = 0; m < 4; ++m)
        #pragma unroll
        for (int n = 0; n < 2; ++n)
            #pragma unroll
            for (int r = 0; r < 4; ++r) acc[m][n][r] = 0.f;

    const int ksteps = (cin + 31) >> 5;
    for (int cs = 0; cs < ksteps; ++cs) {
        const int c0 = cs << 5;
        for (int id = tid; id < 132*4; id += 512) {
            const int row = id >> 2, g = id & 3;
            const int t = t0 + row - 2;
            f16x8 v;
            #pragma unroll
            for (int j = 0; j < 8; ++j) v[j] = (h16)0.f;
            if (t >= 0 && t < T_LEN) {
                const int c = c0 + g*8;
                if (c + 8 <= cin) {
                    v = *(const f16x8*)(Xt + ((size_t)b*T_LEN + t)*cin + c);
                } else if (c < cin) {
                    #pragma unroll
                    for (int j = 0; j < 8; ++j) if (c + j < cin) v[j] = Xt[((size_t)b*T_LEN + t)*cin + c + j];
                }
            }
            *(f16x8*)(Xs + row*40 + g*8) = v;
        }
        for (int id = tid; id < 5*128*4; id += 512) {
            const int k  = id >> 9;
            const int co = (id >> 2) & 127;
            const int g  = id & 3;
            const int c  = c0 + g*8;
            f16x8 v;
            #pragma unroll
            for (int j = 0; j < 8; ++j) v[j] = (h16)0.f;
            if (c + 8 <= cin) {
                v = *(const f16x8*)(Wp + ((size_t)k*512 + co0 + co)*cin + c);
            } else if (c < cin) {
                #pragma unroll
                for (int j = 0; j < 8; ++j) if (c + j < cin) v[j] = Wp[((size_t)k*512 + co0 + co)*cin + c + j];
            }
            *(f16x8*)(Ws + (k*128 + co)*40 + g*8) = v;
        }
        __syncthreads();

        #pragma unroll
        for (int k = 0; k < 5; ++k) {
            const f16x8 b0 = *(const f16x8*)(Ws + (k*128 + wn*32 +      lr)*40 + lg*8);
            const f16x8 b1 = *(const f16x8*)(Ws + (k*128 + wn*32 + 16 + lr)*40 + lg*8);
            #pragma unroll
            for (int m = 0; m < 4; ++m) {
                const f16x8 a = *(const f16x8*)(Xs + (wm*64 + m*16 + lr + k)*40 + lg*8);
                acc[m][0] = __builtin_amdgcn_mfma_f32_16x16x32_f16(a, b0, acc[m][0], 0, 0, 0);
                acc[m][1] = __builtin_amdgcn_mfma_f32_16x16x32_f16(a, b1, acc[m][1], 0, 0, 0);
            }
        }
        __syncthreads();
    }

    #pragma unroll
    for (int nf = 0; nf < 2; ++nf) {
        const int co = co0 + wn*32 + nf*16 + lr;
        const float s  = bg[co] * rsqrtf(fmaxf(bv[co] + 1e-5f, 1e-8f));
        const float sh = (cb[co] - bm[co]) * s + bb[co];
        #pragma unroll
        for (int m = 0; m < 4; ++m) {
            #pragma unroll
            for (int r = 0; r < 4; ++r) {
                const int t = t0 + wm*64 + m*16 + lg*4 + r;
                if (t < T_LEN) {
                    const float y = fixup(clamp_s(fmaxf(acc[m][nf][r]*s + sh, 0.f), 0.f, 60000.f), 0.f);
                    outp[((size_t)b*T_LEN + t)*CCH + co] = (h16)y;
                }
            }
        }
    }
}

// ---------------- gates GEMM (MFMA), one time-chunk, both dirs ----------------
__global__ __attribute__((amdgpu_flat_work_group_size(256,256), amdgpu_waves_per_eu(4,4)))
void gates_mfma_kernel(const h16* __restrict__ Xt,
                       const h16* __restrict__ Wg,
                       const float* __restrict__ bih_f, const float* __restrict__ bhh_f,
                       const float* __restrict__ bih_b, const float* __restrict__ bhh_b,
                       h16* __restrict__ G, int t0f, int t0b)
{
    const int tt   = blockIdx.x;
    const int r0   = blockIdx.y * 128;
    const int b    = blockIdx.z & 31;
    const int dir  = blockIdx.z >> 5;
    const int t0c  = dir ? t0b : t0f;
    const int tid  = threadIdx.x;
    const int lane = tid & 63;
    const int w    = tid >> 6;
    const int lr   = lane & 15;
    const int lg   = lane >> 4;
    const float* bi = dir ? bih_b : bih_f;
    const float* bh = dir ? bhh_b : bhh_f;
    const h16* Wd = Wg + (size_t)dir*1024*512;

    __shared__ __align__(16) h16 Xs[64*40];
    __shared__ __align__(16) h16 Ws[128*40];

    f32x4 acc[4][2];
    #pragma unroll
    for (int m = 0; m < 4; ++m)
        #pragma unroll
        for (int n = 0; n < 2; ++n)
            #pragma unroll
            for (int r = 0; r < 4; ++r) acc[m][n][r] = 0.f;

    for (int cs = 0; cs < 16; ++cs) {
        const int c0 = cs << 5;
        for (int id = tid; id < 64*4; id += 256) {
            const int row = id >> 2, g = id & 3;
            int t = t0c + tt*64 + row; if (t >= T_LEN) t = T_LEN - 1;
            *(f16x8*)(Xs + row*40 + g*8) = *(const f16x8*)(Xt + ((size_t)b*T_LEN + t)*CCH + c0 + g*8);
        }
        for (int id = tid; id < 128*4; id += 256) {
            const int row = id >> 2, g = id & 3;
            *(f16x8*)(Ws + row*40 + g*8) = *(const f16x8*)(Wd + (size_t)(r0 + row)*CCH + c0 + g*8);
        }
        __syncthreads();

        const f16x8 b0 = *(const f16x8*)(Ws + (w*32 +      lr)*40 + lg*8);
        const f16x8 b1 = *(const f16x8*)(Ws + (w*32 + 16 + lr)*40 + lg*8);
        #pragma unroll
        for (int m = 0; m < 4; ++m) {
            const f16x8 a = *(const f16x8*)(Xs + (m*16 + lr)*40 + lg*8);
            acc[m][0] = __builtin_amdgcn_mfma_f32_16x16x32_f16(a, b0, acc[m][0], 0, 0, 0);
            acc[m][1] = __builtin_amdgcn_mfma_f32_16x16x32_f16(a, b1, acc[m][1], 0, 0, 0);
        }
        __syncthreads();
    }

    #pragma unroll
    for (int nf = 0; nf < 2; ++nf) {
        const int row = r0 + w*32 + nf*16 + lr;
        const float bias = bi[row] + bh[row];
        #pragma unroll
        for (int m = 0; m < 4; ++m) {
            #pragma unroll
            for (int r = 0; r < 4; ++r) {
                const int tl = tt*64 + m*16 + lg*4 + r;
                if (tl < TC)
                    G[(((size_t)dir*TC + tl)*NBATCH + b)*GDIM + row]
                        = (h16)fixup(clamp_s(acc[m][nf][r] + bias, -60000.f, 60000.f), 0.f);
            }
        }
    }
}

// ---------------- persistent biLSTM recurrence: int8, weights fully resident ----------------
// Thread t: half=(t>>6)&1 (k-half), q=t>>7, l=t&63; rows rA=q*128+2l, rB=rA+1.
// REGS (hoisted, loop-invariant): rB g0..7 (rb[8]) + rA g7 (ra7) = 36 VGPR.
// LDS: rA g0..6 (7 chunks, 112 KB). Per step: 7 ds_read_b128 + 1 ds_read_b32 + 64 dot4 + 32 readlane.
__global__ __attribute__((amdgpu_flat_work_group_size(1024, 1024), amdgpu_waves_per_eu(4, 4)))
void lstm_chunk_kernel(const h16* __restrict__ G,
                       const unsigned* __restrict__ W8,
                       const float* __restrict__ scl,
                       float* __restrict__ state,
                       float* __restrict__ out,
                       int t0f, int t0b, int first)
{
    const int tid  = threadIdx.x;
    const int lane = tid & 63;
    const int half = (tid >> 6) & 1;
    const int q    = tid >> 7;
    const int dir  = blockIdx.x >> 5;
    const int b    = blockIdx.x & 31;
    const int t0   = dir ? t0b : t0f;
    float* st = state + ((size_t)(dir*NBATCH + b))*2*HDIM;
    const uint4* Wg8 = (const uint4*)W8 + (size_t)dir*16384;   // 16 chunks x 1024 uint4

    __shared__ __align__(16) uint4 lw8[7*1024];        // 112 KB: rowA g0..6
    __shared__ __align__(4)  unsigned char hq8[256];   // h int8
    __shared__ float pbuf[2*GDIM];                     // 8 KB

    // hoisted, loop-invariant weight registers
    uint4 rb[8];
    #pragma unroll
    for (int g = 0; g < 8; ++g) rb[g] = Wg8[g*1024 + tid];     // rowB g0..7
    const uint4 ra7 = Wg8[8*1024 + tid];                       // rowA g7

    #pragma unroll
    for (int s = 0; s < 7; ++s)
        lw8[s*1024 + tid] = Wg8[(9 + s)*1024 + tid];           // rowA g0..6 -> LDS

    const int rA = q*128 + 2*lane;
    const float sclA = scl[dir*1024 + rA];
    const float sclB = scl[dir*1024 + rA + 1];

    float hst = 0.0f, cst = 0.0f;
    if (tid < HDIM) {
        if (!first) { hst = st[tid]; cst = st[HDIM + tid]; }
        const int qh = (int)rintf(clamp_s(hst, -1.f, 1.f) * 127.f);
        hq8[tid] = (unsigned char)(qh & 0xFF);
    }
    __syncthreads();

    float2* pbuf2 = (float2*)pbuf;
    float prev_h = 0.0f;
    int   prev_t = -1;

    for (int i = 0; i < TC; ++i) {
        const int sl = dir ? (TC - 1 - i) : i;
        const int t  = t0 + sl;
        const h16* gp = G + (((size_t)dir*TC + sl)*NBATCH + b)*GDIM;

        const unsigned wv = ((const unsigned*)hq8)[(half << 5) | (lane & 31)];

        float g0 = 0.f, g1 = 0.f, g2 = 0.f, g3 = 0.f;
        if (tid < HDIM) {
            if (prev_t >= 0)
                out[((size_t)b*T_LEN + prev_t)*(2*HDIM) + dir*HDIM + tid] = prev_h;
            g0 = (float)gp[tid];
            g1 = (float)gp[HDIM + tid];
            g2 = (float)gp[2*HDIM + tid];
            g3 = (float)gp[3*HDIM + tid];
        }

        int accA = 0, accB = 0;
        #pragma unroll
        for (int g = 0; g < 8; ++g) {                  // same order as r18: g0..g7 per row
            const int s0 = __builtin_amdgcn_readlane((int)wv, 4*g + 0);
            const int s1 = __builtin_amdgcn_readlane((int)wv, 4*g + 1);
            const int s2 = __builtin_amdgcn_readlane((int)wv, 4*g + 2);
            const int s3 = __builtin_amdgcn_readlane((int)wv, 4*g + 3);
            const uint4 wA = (g < 7) ? lw8[g*1024 + tid] : ra7;
            const uint4 wB = rb[g];
            accA = dot4i8(s0, (int)wA.x, accA);
            accA = dot4i8(s1, (int)wA.y, accA);
            accA = dot4i8(s2, (int)wA.z, accA);
            accA = dot4i8(s3, (int)wA.w, accA);
            accB = dot4i8(s0, (int)wB.x, accB);
            accB = dot4i8(s1, (int)wB.y, accB);
            accB = dot4i8(s2, (int)wB.z, accB);
            accB = dot4i8(s3, (int)wB.w, accB);
        }

        pbuf2[(half << 9) | (q << 6) | lane] = make_float2((float)accA * sclA, (float)accB * sclB);
        __syncthreads();

        if (tid < HDIM) {
            const float gi = g0 + pbuf[tid]            + pbuf[GDIM + tid];
            const float gf = g1 + pbuf[HDIM + tid]     + pbuf[GDIM + HDIM + tid];
            const float gg = g2 + pbuf[2*HDIM + tid]   + pbuf[GDIM + 2*HDIM + tid];
            const float go = g3 + pbuf[3*HDIM + tid]   + pbuf[GDIM + 3*HDIM + tid];
            const float c2 = sigm(gf)*cst + sigm(gi)*tanh_safe(gg);
            const float h2 = sigm(go)*tanh_safe(c2);
            hst = 0.1f*hst + 0.9f*h2;                   // zoneout (output is post-zoneout h)
            cst = 0.1f*cst + 0.9f*c2;
            prev_h = fixup(hst, 50.0f);
            prev_t = t;
            const int qh = (int)rintf(clamp_s(hst, -1.f, 1.f) * 127.f);
            hq8[tid] = (unsigned char)(qh & 0xFF);      // next step's recurrent h (int8)
        }
        __syncthreads();
    }

    if (tid < HDIM) {
        if (prev_t >= 0)
            out[((size_t)b*T_LEN + prev_t)*(2*HDIM) + dir*HDIM + tid] = prev_h;
        st[tid] = hst; st[HDIM + tid] = cst;
    }
}

extern "C" void kernel_launch(void* const* d_in, const int* in_sizes, int n_in,
                              void* d_out, int out_size, void* d_ws, size_t ws_size,
                              hipStream_t stream)
{
    (void)in_sizes; (void)n_in; (void)out_size;
    if (ws_size < 49152000) return;

    const float* x     = (const float*)d_in[0];
    const float* cw0   = (const float*)d_in[1];
    const float* cb0   = (const float*)d_in[2];
    const float* bg0   = (const float*)d_in[3];
    const float* bb0   = (const float*)d_in[4];
    const float* bm0   = (const float*)d_in[5];
    const float* bv0   = (const float*)d_in[6];
    const float* cw1   = (const float*)d_in[7];
    const float* cb1   = (const float*)d_in[8];
    const float* bg1   = (const float*)d_in[9];
    const float* bb1   = (const float*)d_in[10];
    const float* bm1   = (const float*)d_in[11];
    const float* bv1   = (const float*)d_in[12];
    const float* cw2   = (const float*)d_in[13];
    const float* cb2   = (const float*)d_in[14];
    const float* bg2   = (const float*)d_in[15];
    const float* bb2   = (const float*)d_in[16];
    const float* bm2   = (const float*)d_in[17];
    const float* bv2   = (const float*)d_in[18];
    const float* wih_f = (const float*)d_in[19];
    const float* whh_f = (const float*)d_in[20];
    const float* bih_f = (const float*)d_in[21];
    const float* bhh_f = (const float*)d_in[22];
    const float* wih_b = (const float*)d_in[23];
    const float* whh_b = (const float*)d_in[24];
    const float* bih_b = (const float*)d_in[25];
    const float* bhh_b = (const float*)d_in[26];

    char* ws = (char*)d_ws;
    char* od = (char*)d_out;
    h16*      A   = (h16*)(ws);
    h16*      G   = (h16*)(ws + 32768000);
    float*    st  = (float*)(ws + 45875200);
    unsigned* W8  = (unsigned*)(ws + 46006272);
    float*    scl = (float*)(ws + 46530560);
    h16*      Wg  = (h16*)(ws + 47054848);
    h16*      Bd  = (h16*)(od);
    h16*      Wp0 = (h16*)(od + 36000000);
    h16*      Wp1 = (h16*)(od + 36409600);
    h16*      Wp2 = (h16*)(od + 41652480);
    h16*      Xt0 = (h16*)(od + 46895360);
    float*    out = (float*)d_out;

    // packs
    pack_convw_kernel<<<dim3((5*512*80  + 255)/256), 256, 0, stream>>>(cw0, Wp0, 80);
    pack_convw_kernel<<<dim3((5*512*512 + 255)/256), 256, 0, stream>>>(cw1, Wp1, 512);
    pack_convw_kernel<<<dim3((5*512*512 + 255)/256), 256, 0, stream>>>(cw2, Wp2, 512);
    pack_wih_kernel<<<dim3(2*1024*512/256), 256, 0, stream>>>(wih_f, wih_b, Wg);
    whh_scale_kernel<<<dim3(8), 256, 0, stream>>>(whh_f, whh_b, scl);
    whh_prep_kernel<<<dim3(512), 256, 0, stream>>>(whh_f, whh_b, scl, W8);
    x0_transpose_kernel<<<dim3(4, 32), 256, 0, stream>>>(x, Xt0);

    // convs (implicit-GEMM MFMA)
    const dim3 cgrid(8, 4, 32);
    conv_mfma_kernel<<<cgrid, 512, 0, stream>>>(Xt0, Wp0, A,  cb0, bg0, bb0, bm0, bv0, 80);
    conv_mfma_kernel<<<cgrid, 512, 0, stream>>>(A,   Wp1, Bd, cb1, bg1, bb1, bm1, bv1, 512);
    conv_mfma_kernel<<<cgrid, 512, 0, stream>>>(Bd,  Wp2, A,  cb2, bg2, bb2, bm2, bv2, 512);

    for (int c = 0; c < T_LEN / TC; ++c) {
        const int t0f = c * TC;
        const int t0b = (T_LEN - TC) - c * TC;
        gates_mfma_kernel<<<dim3(2, 8, 64), 256, 0, stream>>>(A, Wg, bih_f, bhh_f, bih_b, bhh_b, G, t0f, t0b);
        lstm_chunk_kernel<<<dim3(64), 1024, 0, stream>>>(G, W8, scl, st, out, t0f, t0b, c == 0);
    }
}